// Round 6
// baseline (1133.444 us; speedup 1.0000x reference)
//
#include <hip/hip_runtime.h>
#include <hip/hip_bf16.h>

// LSAPPNP: h = relu(x@W1+b1); h2 = h@W2+b2; agg[r] += val*h2[c] over edges;
// out = log_softmax(0.1*h2 + agg, axis=1)
// N=100000, F_IN=500, HID=256, C=40, E~2.3M
//
// Round 12: no-sort edge pipeline. R11 showed row-granular scatter = 8x
// write amplification (100K open lines thrash L2). Replace hist/scan/
// scatter with: (a) fixed-capacity bucket append (782 buckets = 100KB of
// open lines, padded per-line atomic counters, no scan needed);
// (b) per-thread-per-edge bucket SpMM with LDS f32 accumulator
// (stride-41 bank spread) + fused softmax. MLP kept at R8 (128.8us).

#define N_NODES 100000
#define F_IN    500
#define HID     256
#define C_OUT   40
#define ALPHA0  0.1f
#define H2STRIDE 64

#define RPB     128                           // rows per bucket
#define NBUCK   ((N_NODES + RPB - 1) / RPB)   // 782
#define BCAP    4096                          // bucket capacity (mean 2945, std 54)

typedef short short8 __attribute__((ext_vector_type(8)));
typedef float f32x4  __attribute__((ext_vector_type(4)));

__device__ __forceinline__ short f2bf(float f) {
  union { float f; unsigned u; } x; x.f = f;
  unsigned r = x.u + 0x7fffu + ((x.u >> 16) & 1u);  // RNE
  return (short)(r >> 16);
}
__device__ __forceinline__ float bf2f(short s) {
  union { unsigned u; float f; } x; x.u = ((unsigned)(unsigned short)s) << 16;
  return x.f;
}
// packed f32x2 -> bf16x2 (RNE), single VOP3
__device__ __forceinline__ unsigned cvtpk(float lo, float hi) {
  unsigned r;
  asm("v_cvt_pk_bf16_f32 %0, %1, %2" : "=v"(r) : "v"(lo), "v"(hi));
  return r;
}
// LDS-only barrier: drain DS ops, then raw s_barrier (no vmcnt drain).
__device__ __forceinline__ void lbar() {
  asm volatile("s_waitcnt lgkmcnt(0)" ::: "memory");
  __builtin_amdgcn_s_barrier();
}
// async global->LDS, 16B per lane; LDS dest = wave-uniform base + lane*16
__device__ __forceinline__ void gll16(const float* g, const char* l) {
  __builtin_amdgcn_global_load_lds(
      (const __attribute__((address_space(1))) void*)g,
      (__attribute__((address_space(3))) void*)l, 16, 0, 0);
}

// ---- K0: pack W1 -> W1S [16 kc][256 n][32 k] bf16; W2 -> W2T [48 n][256 k];
//          zero the padded bucket counters (one 128B line each).
__global__ __launch_bounds__(256) void k_pack_weights(
    const float* __restrict__ W1, const float* __restrict__ W2,
    short* __restrict__ W1S, short* __restrict__ W2T,
    int* __restrict__ bcnt)
{
  int i = blockIdx.x * 256 + threadIdx.x;
  if (i < 16*256*32) {
    int kc  = i >> 13;
    int idx = i & 8191;
    int n   = idx >> 5;
    int kk  = idx & 31;
    int k   = kc*32 + kk;
    float v = (k < F_IN) ? W1[k*HID + n] : 0.f;
    W1S[i] = f2bf(v);
  } else if (i < 16*256*32 + 48*256) {
    int j = i - 16*256*32;
    int n = j >> 8;
    int k = j & 255;
    float v = (n < C_OUT) ? W2[k*C_OUT + n] : 0.f;
    W2T[j] = f2bf(v);
  } else {
    int j = i - (16*256*32 + 48*256);
    if (j < NBUCK * 32) bcnt[j] = 0;
  }
}

// ---- K1: fused MLP (R8 structure: gll f32 staging, counted vmcnt, no full
// syncthreads in K loop). 512 thr = 8 waves (2 row x 4 col), tile 128x256.
__global__ __launch_bounds__(512, 4) void k_fused_mlp(
    const float* __restrict__ x, const float* __restrict__ b1v,
    const float* __restrict__ b2v,
    const short* __restrict__ W1S, const short* __restrict__ W2T,
    short* __restrict__ h2b)
{
  __shared__ __align__(16) char smem[65536];
  short (*Hl)[256] = (short(*)[256])smem;   // post-loop overlay, 64KB

  const int tid  = threadIdx.x;
  const int w    = tid >> 6;
  const int lane = tid & 63;
  const int lr   = lane & 15;
  const int quad = lane >> 4;
  const int wr   = w >> 2;      // 0..1 row-wave
  const int wc   = w & 3;       // 0..3 col-wave
  const int row0 = blockIdx.x * 128;

  const int s_rl0 = (w*2)*8 + (lane>>3);
  const int s_rl1 = (w*2+1)*8 + (lane>>3);
  const int ksw   = ((lane&7) ^ ((lane>>3)&7)) * 4;
  const float* gp0 = x + (size_t)min(row0 + s_rl0, N_NODES-1) * F_IN;
  const float* gp1 = x + (size_t)min(row0 + s_rl1, N_NODES-1) * F_IN;
  const char* l0 = smem + (w*2)*1024;       // + buf*16384
  const char* l1 = smem + (w*2+1)*1024;

  f32x4 acc[4][4] = {};

  #pragma unroll
  for (int p = 0; p < 2; ++p) {
    int kb = p*32 + ksw;
    const float* a0 = (kb + 4 <= F_IN) ? gp0 + kb : x;
    const float* a1 = (kb + 4 <= F_IN) ? gp1 + kb : x;
    gll16(a0, l0 + p*16384);
    gll16(a1, l1 + p*16384);
  }

  const short* bbase = W1S + (wc*64 + lr)*32 + quad*8;
  const int m2 = lr & 7;

  #pragma unroll
  for (int kc = 0; kc < 16; ++kc) {
    short8 bf4[4];
    #pragma unroll
    for (int t = 0; t < 4; ++t)
      bf4[t] = *(const short8*)(bbase + kc*8192 + t*16*32);
    __builtin_amdgcn_sched_barrier(0);

    if (kc < 14) {
      int kb = (kc+2)*32 + ksw;
      const float* a0 = (kb + 4 <= F_IN) ? gp0 + kb : x;
      const float* a1 = (kb + 4 <= F_IN) ? gp1 + kb : x;
      gll16(a0, l0 + ((kc+2)&3)*16384);
      gll16(a1, l1 + ((kc+2)&3)*16384);
      __builtin_amdgcn_sched_barrier(0);
      asm volatile("s_waitcnt vmcnt(8)" ::: "memory");
    } else if (kc == 14) {
      asm volatile("s_waitcnt vmcnt(6)" ::: "memory");
    } else {
      asm volatile("s_waitcnt vmcnt(4)" ::: "memory");
    }
    __builtin_amdgcn_s_barrier();

    const char* Abase = smem + (kc & 3)*16384;
    short8 af[4];
    #pragma unroll
    for (int t = 0; t < 4; ++t) {
      int rl = wr*64 + t*16 + lr;
      f32x4 u0 = *(const f32x4*)(Abase + rl*128 + (((quad*2  ) ^ m2) << 4));
      f32x4 u1 = *(const f32x4*)(Abase + rl*128 + (((quad*2+1) ^ m2) << 4));
      union { unsigned u[4]; short8 s; } pk;
      pk.u[0] = cvtpk(u0[0], u0[1]);
      pk.u[1] = cvtpk(u0[2], u0[3]);
      pk.u[2] = cvtpk(u1[0], u1[1]);
      pk.u[3] = cvtpk(u1[2], u1[3]);
      af[t] = pk.s;
    }

    #pragma unroll
    for (int rt = 0; rt < 4; ++rt)
      #pragma unroll
      for (int ct = 0; ct < 4; ++ct)
        acc[rt][ct] = __builtin_amdgcn_mfma_f32_16x16x32_bf16(af[rt], bf4[ct], acc[rt][ct], 0, 0, 0);
  }
  lbar();

  #pragma unroll
  for (int ct = 0; ct < 4; ++ct) {
    int col = wc*64 + ct*16 + lr;
    int cg = col >> 3, ci = col & 7;
    float bias = b1v[col];
    #pragma unroll
    for (int rt = 0; rt < 4; ++rt) {
      #pragma unroll
      for (int r = 0; r < 4; ++r) {
        int row = wr*64 + rt*16 + quad*4 + r;
        float v = fmaxf(acc[rt][ct][r] + bias, 0.f);
        Hl[row][((cg ^ (row & 31)) << 3) | ci] = f2bf(v);
      }
    }
  }
  lbar();

  f32x4 acc2[3] = {};
  const int arow = w*16 + lr;
  #pragma unroll
  for (int kc2 = 0; kc2 < 8; ++kc2) {
    int gg = kc2*4 + quad;
    short8 a2 = *(const short8*)&Hl[arow][(gg ^ (arow & 31)) << 3];
    #pragma unroll
    for (int nt = 0; nt < 3; ++nt) {
      short8 b2 = *(const short8*)(W2T + (nt*16 + lr)*256 + kc2*32 + quad*8);
      acc2[nt] = __builtin_amdgcn_mfma_f32_16x16x32_bf16(a2, b2, acc2[nt], 0, 0, 0);
    }
  }

  #pragma unroll
  for (int nt = 0; nt < 3; ++nt) {
    int col = nt*16 + lr;
    float bias = (col < C_OUT) ? b2v[col] : 0.f;
    #pragma unroll
    for (int r = 0; r < 4; ++r) {
      int row = row0 + w*16 + quad*4 + r;
      if (row < N_NODES) {
        float v = (col < C_OUT) ? (acc2[nt][r] + bias) : 0.f;
        h2b[(long)row * H2STRIDE + col] = f2bf(v);
      }
    }
  }
  {
    int col = 48 + lr;
    #pragma unroll
    for (int r = 0; r < 4; ++r) {
      int row = row0 + w*16 + quad*4 + r;
      if (row < N_NODES) h2b[(long)row * H2STRIDE + col] = 0;
    }
  }
}

// ---- K2: fixed-capacity bucket append. 782 buckets, cursors padded to one
// 128B line each. Per-bucket appends are monotone -> ~782 open output lines
// (L2-friendly, no write amplification). No hist/scan needed.
__global__ __launch_bounds__(256) void k_bucket_append(
    const int* __restrict__ erow, const int* __restrict__ ecol,
    const float* __restrict__ eval, int* __restrict__ bcnt,
    int2* __restrict__ bedges, int E)
{
  int i = blockIdx.x * 256 + threadIdx.x;
  int stride = gridDim.x * 256;
  for (int e = i; e < E; e += stride) {
    int r = erow[e];
    int b = r >> 7;
    int pos = atomicAdd(&bcnt[b * 32], 1);
    if (pos < BCAP) {
      int2 cv;
      cv.x = ecol[e] | ((r & 127) << 17);
      cv.y = __float_as_int(eval[e]);
      bedges[(size_t)b * BCAP + pos] = cv;
    }
  }
}

// ---- K3: bucket SpMM + fused log_softmax. One block (4 waves) per bucket.
// One edge per THREAD (fixes R10's edge-per-wave serialization): coalesced
// int2 read, 5x16B gather of the h2b line, 40x ds_add_f32 into stride-41
// LDS accumulator (banks = (rl*9+c)%32, conflict-light for random rl).
__global__ __launch_bounds__(256) void k_spmm_bucket2(
    const int* __restrict__ bcnt, const int2* __restrict__ bedges,
    const short* __restrict__ h2b, float* __restrict__ out)
{
  __shared__ float accL[RPB][41];   // 20992 B
  int tid = threadIdx.x, b = blockIdx.x;
  int lane = tid & 63, w = tid >> 6;
  int cnt = min(bcnt[b * 32], BCAP);
  const int2* ep = bedges + (size_t)b * BCAP;

  for (int i = tid; i < RPB * 41; i += 256) ((float*)accL)[i] = 0.f;
  __syncthreads();

  for (int e = tid; e < cnt; e += 256) {
    int2 cv = ep[e];
    int c  = cv.x & 0x1FFFF;
    int rl = ((unsigned)cv.x) >> 17;
    float v = __int_as_float(cv.y);
    const short8* hp = (const short8*)(h2b + (size_t)c * H2STRIDE);
    short8 s0 = hp[0];
    short8 s1 = hp[1];
    short8 s2 = hp[2];
    short8 s3 = hp[3];
    short8 s4 = hp[4];
    float* arow = accL[rl];
    #pragma unroll
    for (int j = 0; j < 8; ++j) atomicAdd(&arow[j],      v * bf2f(s0[j]));
    #pragma unroll
    for (int j = 0; j < 8; ++j) atomicAdd(&arow[8 + j],  v * bf2f(s1[j]));
    #pragma unroll
    for (int j = 0; j < 8; ++j) atomicAdd(&arow[16 + j], v * bf2f(s2[j]));
    #pragma unroll
    for (int j = 0; j < 8; ++j) atomicAdd(&arow[24 + j], v * bf2f(s3[j]));
    #pragma unroll
    for (int j = 0; j < 8; ++j) atomicAdd(&arow[32 + j], v * bf2f(s4[j]));
  }
  __syncthreads();

  // epilogue: wave w handles rows w*32 .. +31 of the bucket
  for (int rr = 0; rr < 32; ++rr) {
    int r = w*32 + rr;
    int row = b * RPB + r;
    if (row >= N_NODES) continue;
    float a = -INFINITY;
    if (lane < C_OUT)
      a = accL[r][lane] + ALPHA0 * bf2f(h2b[(size_t)row * H2STRIDE + lane]);
    float m = a;
    #pragma unroll
    for (int o = 32; o > 0; o >>= 1) m = fmaxf(m, __shfl_xor(m, o));
    float ev = (lane < C_OUT) ? __expf(a - m) : 0.f;
    float s = ev;
    #pragma unroll
    for (int o = 32; o > 0; o >>= 1) s += __shfl_xor(s, o);
    if (lane < C_OUT) out[(long)row * C_OUT + lane] = a - m - __logf(s);
  }
}

extern "C" void kernel_launch(void* const* d_in, const int* in_sizes, int n_in,
                              void* d_out, int out_size, void* d_ws, size_t ws_size,
                              hipStream_t stream) {
  const float* x    = (const float*)d_in[0];
  const float* W1   = (const float*)d_in[1];
  const float* b1   = (const float*)d_in[2];
  const float* W2   = (const float*)d_in[3];
  const float* b2   = (const float*)d_in[4];
  const int*   erow = (const int*)d_in[5];
  const int*   ecol = (const int*)d_in[6];
  const float* eval = (const float*)d_in[7];
  const int E  = in_sizes[5];

  // ws: h2b 12.8MB | W1S 256KB | W2T 24KB | bcnt 100KB | bedges 25.6MB (~39MB)
  char* p = (char*)d_ws;
  short* h2b    = (short*)p;  p += (size_t)N_NODES * H2STRIDE * 2;
  short* W1S    = (short*)p;  p += (size_t)16*256*32 * 2;
  short* W2T    = (short*)p;  p += (size_t)48*256 * 2;
  int*   bcnt   = (int*)p;    p += (size_t)NBUCK * 32 * 4;
  int2*  bedges = (int2*)p;
  float* out = (float*)d_out;

  const int pack_work = 16*256*32 + 48*256 + NBUCK*32;
  k_pack_weights<<<(pack_work + 255)/256, 256, 0, stream>>>(W1, W2, W1S, W2T, bcnt);
  k_fused_mlp<<<(N_NODES + 127)/128, 512, 0, stream>>>(x, b1, b2, W1S, W2T, h2b);
  k_bucket_append<<<2048, 256, 0, stream>>>(erow, ecol, eval, bcnt, bedges, E);
  k_spmm_bucket2<<<NBUCK, 256, 0, stream>>>(bcnt, bedges, h2b, out);
}

// Round 7
// 528.517 us; speedup vs baseline: 2.1446x; 2.1446x over previous
//
#include <hip/hip_runtime.h>
#include <hip/hip_bf16.h>

// LSAPPNP: h = relu(x@W1+b1); h2 = h@W2+b2; agg[r] += val*h2[c] over edges;
// out = log_softmax(0.1*h2 + agg, axis=1)
// N=100000, F_IN=500, HID=256, C=40, E~2.3M
//
// Round 13: recover R2 winner (546.8us) + consolidate edge pipeline.
// Lessons: 2.3M global atomics = ~280us floor (R11/R12) -> zero global
// atomics. Pipeline: hist2 (LDS) -> scan1 -> split (in-LDS block-sum
// prefix, emits bstart; scan2/scan3 deleted) -> fused csr+spmm (bucket
// edges staged to regs -> LDS row-sort -> wave-per-row SpMM from LDS).
// RPB=64 (1563 blocks, 6.1/CU) fixes grid tail. 6 launches (was 8),
// ~55MB less traffic. MLP byte-identical R8 (128.8us measured).

#define N_NODES 100000
#define F_IN    500
#define HID     256
#define C_OUT   40
#define ALPHA0  0.1f
#define H2STRIDE 64

#define RPB     64                            // rows per bucket
#define NBUCK   ((N_NODES + RPB - 1) / RPB)   // 1563
#define NCH     320                           // edge chunks (hist/split blocks)
#define SCAN_M  (NBUCK * NCH)                 // 500160
#define SCAN_CHUNK 2048
#define NBS     ((SCAN_M + SCAN_CHUNK - 1) / SCAN_CHUNK)  // 245
#define BCAPL   1792                          // bucket cap (mean 1474, +8.3 sigma)

typedef short short8 __attribute__((ext_vector_type(8)));
typedef float f32x4  __attribute__((ext_vector_type(4)));

__device__ __forceinline__ short f2bf(float f) {
  union { float f; unsigned u; } x; x.f = f;
  unsigned r = x.u + 0x7fffu + ((x.u >> 16) & 1u);  // RNE
  return (short)(r >> 16);
}
__device__ __forceinline__ float bf2f(short s) {
  union { unsigned u; float f; } x; x.u = ((unsigned)(unsigned short)s) << 16;
  return x.f;
}
// packed f32x2 -> bf16x2 (RNE), single VOP3
__device__ __forceinline__ unsigned cvtpk(float lo, float hi) {
  unsigned r;
  asm("v_cvt_pk_bf16_f32 %0, %1, %2" : "=v"(r) : "v"(lo), "v"(hi));
  return r;
}
// LDS-only barrier: drain DS ops, then raw s_barrier (no vmcnt drain).
__device__ __forceinline__ void lbar() {
  asm volatile("s_waitcnt lgkmcnt(0)" ::: "memory");
  __builtin_amdgcn_s_barrier();
}
// async global->LDS, 16B per lane; LDS dest = wave-uniform base + lane*16
__device__ __forceinline__ void gll16(const float* g, const char* l) {
  __builtin_amdgcn_global_load_lds(
      (const __attribute__((address_space(1))) void*)g,
      (__attribute__((address_space(3))) void*)l, 16, 0, 0);
}

// ---- K0: pack W1 -> W1S [16 kc][256 n][32 k] bf16; W2 -> W2T [48 n][256 k]
__global__ __launch_bounds__(256) void k_pack_weights(
    const float* __restrict__ W1, const float* __restrict__ W2,
    short* __restrict__ W1S, short* __restrict__ W2T)
{
  int i = blockIdx.x * 256 + threadIdx.x;
  if (i < 16*256*32) {
    int kc  = i >> 13;
    int idx = i & 8191;
    int n   = idx >> 5;
    int kk  = idx & 31;
    int k   = kc*32 + kk;
    float v = (k < F_IN) ? W1[k*HID + n] : 0.f;
    W1S[i] = f2bf(v);
  } else {
    int j = i - 16*256*32;
    if (j < 48*256) {
      int n = j >> 8;
      int k = j & 255;
      float v = (n < C_OUT) ? W2[k*C_OUT + n] : 0.f;
      W2T[j] = f2bf(v);
    }
  }
}

// ---- K1: fused MLP (R8 structure: gll f32 staging, counted vmcnt, no full
// syncthreads in K loop). 512 thr = 8 waves (2 row x 4 col), tile 128x256.
__global__ __launch_bounds__(512, 4) void k_fused_mlp(
    const float* __restrict__ x, const float* __restrict__ b1v,
    const float* __restrict__ b2v,
    const short* __restrict__ W1S, const short* __restrict__ W2T,
    short* __restrict__ h2b)
{
  __shared__ __align__(16) char smem[65536];
  short (*Hl)[256] = (short(*)[256])smem;   // post-loop overlay, 64KB

  const int tid  = threadIdx.x;
  const int w    = tid >> 6;
  const int lane = tid & 63;
  const int lr   = lane & 15;
  const int quad = lane >> 4;
  const int wr   = w >> 2;      // 0..1 row-wave
  const int wc   = w & 3;       // 0..3 col-wave
  const int row0 = blockIdx.x * 128;

  const int s_rl0 = (w*2)*8 + (lane>>3);
  const int s_rl1 = (w*2+1)*8 + (lane>>3);
  const int ksw   = ((lane&7) ^ ((lane>>3)&7)) * 4;
  const float* gp0 = x + (size_t)min(row0 + s_rl0, N_NODES-1) * F_IN;
  const float* gp1 = x + (size_t)min(row0 + s_rl1, N_NODES-1) * F_IN;
  const char* l0 = smem + (w*2)*1024;       // + buf*16384
  const char* l1 = smem + (w*2+1)*1024;

  f32x4 acc[4][4] = {};

  #pragma unroll
  for (int p = 0; p < 2; ++p) {
    int kb = p*32 + ksw;
    const float* a0 = (kb + 4 <= F_IN) ? gp0 + kb : x;
    const float* a1 = (kb + 4 <= F_IN) ? gp1 + kb : x;
    gll16(a0, l0 + p*16384);
    gll16(a1, l1 + p*16384);
  }

  const short* bbase = W1S + (wc*64 + lr)*32 + quad*8;
  const int m2 = lr & 7;

  #pragma unroll
  for (int kc = 0; kc < 16; ++kc) {
    short8 bf4[4];
    #pragma unroll
    for (int t = 0; t < 4; ++t)
      bf4[t] = *(const short8*)(bbase + kc*8192 + t*16*32);
    __builtin_amdgcn_sched_barrier(0);

    if (kc < 14) {
      int kb = (kc+2)*32 + ksw;
      const float* a0 = (kb + 4 <= F_IN) ? gp0 + kb : x;
      const float* a1 = (kb + 4 <= F_IN) ? gp1 + kb : x;
      gll16(a0, l0 + ((kc+2)&3)*16384);
      gll16(a1, l1 + ((kc+2)&3)*16384);
      __builtin_amdgcn_sched_barrier(0);
      asm volatile("s_waitcnt vmcnt(8)" ::: "memory");
    } else if (kc == 14) {
      asm volatile("s_waitcnt vmcnt(6)" ::: "memory");
    } else {
      asm volatile("s_waitcnt vmcnt(4)" ::: "memory");
    }
    __builtin_amdgcn_s_barrier();

    const char* Abase = smem + (kc & 3)*16384;
    short8 af[4];
    #pragma unroll
    for (int t = 0; t < 4; ++t) {
      int rl = wr*64 + t*16 + lr;
      f32x4 u0 = *(const f32x4*)(Abase + rl*128 + (((quad*2  ) ^ m2) << 4));
      f32x4 u1 = *(const f32x4*)(Abase + rl*128 + (((quad*2+1) ^ m2) << 4));
      union { unsigned u[4]; short8 s; } pk;
      pk.u[0] = cvtpk(u0[0], u0[1]);
      pk.u[1] = cvtpk(u0[2], u0[3]);
      pk.u[2] = cvtpk(u1[0], u1[1]);
      pk.u[3] = cvtpk(u1[2], u1[3]);
      af[t] = pk.s;
    }

    #pragma unroll
    for (int rt = 0; rt < 4; ++rt)
      #pragma unroll
      for (int ct = 0; ct < 4; ++ct)
        acc[rt][ct] = __builtin_amdgcn_mfma_f32_16x16x32_bf16(af[rt], bf4[ct], acc[rt][ct], 0, 0, 0);
  }
  lbar();

  #pragma unroll
  for (int ct = 0; ct < 4; ++ct) {
    int col = wc*64 + ct*16 + lr;
    int cg = col >> 3, ci = col & 7;
    float bias = b1v[col];
    #pragma unroll
    for (int rt = 0; rt < 4; ++rt) {
      #pragma unroll
      for (int r = 0; r < 4; ++r) {
        int row = wr*64 + rt*16 + quad*4 + r;
        float v = fmaxf(acc[rt][ct][r] + bias, 0.f);
        Hl[row][((cg ^ (row & 31)) << 3) | ci] = f2bf(v);
      }
    }
  }
  lbar();

  f32x4 acc2[3] = {};
  const int arow = w*16 + lr;
  #pragma unroll
  for (int kc2 = 0; kc2 < 8; ++kc2) {
    int gg = kc2*4 + quad;
    short8 a2 = *(const short8*)&Hl[arow][(gg ^ (arow & 31)) << 3];
    #pragma unroll
    for (int nt = 0; nt < 3; ++nt) {
      short8 b2 = *(const short8*)(W2T + (nt*16 + lr)*256 + kc2*32 + quad*8);
      acc2[nt] = __builtin_amdgcn_mfma_f32_16x16x32_bf16(a2, b2, acc2[nt], 0, 0, 0);
    }
  }

  #pragma unroll
  for (int nt = 0; nt < 3; ++nt) {
    int col = nt*16 + lr;
    float bias = (col < C_OUT) ? b2v[col] : 0.f;
    #pragma unroll
    for (int r = 0; r < 4; ++r) {
      int row = row0 + w*16 + quad*4 + r;
      if (row < N_NODES) {
        float v = (col < C_OUT) ? (acc2[nt][r] + bias) : 0.f;
        h2b[(long)row * H2STRIDE + col] = f2bf(v);
      }
    }
  }
  {
    int col = 48 + lr;
    #pragma unroll
    for (int r = 0; r < 4; ++r) {
      int row = row0 + w*16 + quad*4 + r;
      if (row < N_NODES) h2b[(long)row * H2STRIDE + col] = 0;
    }
  }
}

// ---- K2: per-chunk LDS histogram of buckets (row>>6). offs[b*NCH + c] = count
__global__ __launch_bounds__(256) void k_hist2(
    const int* __restrict__ erow, int* __restrict__ offs, int E, int CH)
{
  __shared__ int h[NBUCK];
  int tid = threadIdx.x, c = blockIdx.x;
  for (int b = tid; b < NBUCK; b += 256) h[b] = 0;
  __syncthreads();
  int e0 = c * CH, e1 = min(E, e0 + CH);
  for (int e = e0 + tid; e < e1; e += 256)
    atomicAdd(&h[erow[e] >> 6], 1);
  __syncthreads();
  for (int b = tid; b < NBUCK; b += 256) offs[b * NCH + c] = h[b];
}

// ---- K3: scan phase 1 — 2048-elem chunks, in-place exclusive scan + sums
__global__ __launch_bounds__(256) void k_scan1(
    int* __restrict__ offs, int* __restrict__ bsums)
{
  __shared__ int sh[256];
  int tid = threadIdx.x;
  int base = blockIdx.x * SCAN_CHUNK + tid * 8;
  int d[8];
  #pragma unroll
  for (int k = 0; k < 8; ++k)
    d[k] = (base + k < SCAN_M) ? offs[base + k] : 0;
  int s = 0;
  #pragma unroll
  for (int k = 0; k < 8; ++k) s += d[k];
  sh[tid] = s;
  __syncthreads();
  for (int o = 1; o < 256; o <<= 1) {
    int v = (tid >= o) ? sh[tid - o] : 0;
    __syncthreads();
    if (tid >= o) sh[tid] += v;
    __syncthreads();
  }
  int run = sh[tid] - s;
  #pragma unroll
  for (int k = 0; k < 8; ++k) {
    if (base + k < SCAN_M) offs[base + k] = run;
    run += d[k];
  }
  if (tid == 255) bsums[blockIdx.x] = sh[255];
}

// ---- K4: split edges into bucket-grouped order. Absolute cursors derived
// in-block: cur[b] = offs[b*NCH+c] + prefix(bsums)[(b*NCH+c)>>11].
// Block c==0 also emits bstart[] (bucket start offsets). No scan2/scan3.
__global__ __launch_bounds__(256) void k_split(
    const int* __restrict__ erow, const int* __restrict__ ecol,
    const float* __restrict__ eval, const int* __restrict__ offs,
    const int* __restrict__ bsums, int2* __restrict__ sorted,
    int* __restrict__ bstart, int E, int CH)
{
  __shared__ int P[256];
  __shared__ int cur[NBUCK];
  int tid = threadIdx.x, c = blockIdx.x;

  // exclusive prefix of the NBS block sums
  int v = (tid < NBS) ? bsums[tid] : 0;
  P[tid] = v;
  __syncthreads();
  for (int o = 1; o < 256; o <<= 1) {
    int u = (tid >= o) ? P[tid - o] : 0;
    __syncthreads();
    if (tid >= o) P[tid] += u;
    __syncthreads();
  }
  int incl = P[tid];
  __syncthreads();
  P[tid] = incl - v;
  __syncthreads();

  for (int b = tid; b < NBUCK; b += 256) {
    int m = b * NCH + c;
    int val = offs[m] + P[m >> 11];
    cur[b] = val;
    if (c == 0) bstart[b] = val;
  }
  if (c == 0 && tid == 0) bstart[NBUCK] = E;
  __syncthreads();

  int e0 = c * CH, e1 = min(E, e0 + CH);
  for (int e = e0 + tid; e < e1; e += 256) {
    int r = erow[e];
    int b = r >> 6;
    int pos = atomicAdd(&cur[b], 1);
    int2 cv;
    cv.x = ecol[e] | ((r & 63) << 17);
    cv.y = __float_as_int(eval[e]);
    sorted[pos] = cv;
  }
}

// ---- K5: fused per-bucket CSR sort (in LDS) + wave-per-row SpMM + softmax.
// One block (4 waves) per 64-row bucket. Edges staged global->regs once,
// row-sorted into 14KB LDS, then each wave serially processes 16 rows with
// full-wave 128B h2b line gathers per edge (proven pattern).
__global__ __launch_bounds__(256) void k_csr_spmm(
    const int* __restrict__ bstart, const int2* __restrict__ sorted,
    const short* __restrict__ h2b, float* __restrict__ out)
{
  __shared__ int2 eS[BCAPL];      // 14336 B
  __shared__ int h[RPB];
  __shared__ int roff[RPB];       // inclusive scan
  __shared__ int cur[RPB];
  int tid = threadIdx.x, b = blockIdx.x;
  int lane = tid & 63, w = tid >> 6;
  int start = bstart[b], end = bstart[b + 1];
  int cnt = end - start;

  // stage bucket edges into registers (<= 7 per thread)
  int2 cv[7];
  int nloc = 0;
  for (int i = tid, k = 0; i < cnt; i += 256, ++k) { cv[k] = sorted[start + i]; nloc = k + 1; }

  if (tid < RPB) h[tid] = 0;
  __syncthreads();
  for (int k = 0; k < nloc; ++k)
    atomicAdd(&h[((unsigned)cv[k].x) >> 17], 1);
  __syncthreads();
  if (tid < RPB) roff[tid] = h[tid];
  __syncthreads();
  for (int o = 1; o < RPB; o <<= 1) {
    int u = (tid >= o && tid < RPB) ? roff[tid - o] : 0;
    __syncthreads();
    if (tid >= o && tid < RPB) roff[tid] += u;
    __syncthreads();
  }
  if (tid < RPB) cur[tid] = roff[tid] - h[tid];   // exclusive start
  __syncthreads();
  for (int k = 0; k < nloc; ++k) {
    unsigned rl = ((unsigned)cv[k].x) >> 17;
    int p = atomicAdd(&cur[rl], 1);
    if (p < BCAPL) eS[p] = cv[k];
  }
  __syncthreads();

  // SpMM: wave w handles rows w*16 .. +15
  for (int rr = 0; rr < 16; ++rr) {
    int r = w * 16 + rr;
    int row = b * RPB + r;
    if (row >= N_NODES) continue;
    float acc = ALPHA0 * bf2f(h2b[(size_t)row * H2STRIDE + lane]);  // 0 for lane>=40
    int e  = roff[r] - h[r];
    int ee = roff[r];
    for (; e + 3 < ee; e += 4) {
      int2 c0 = eS[e], c1 = eS[e+1], c2 = eS[e+2], c3 = eS[e+3];
      float g0 = bf2f(h2b[(size_t)(c0.x & 0x1FFFF) * H2STRIDE + lane]);
      float g1 = bf2f(h2b[(size_t)(c1.x & 0x1FFFF) * H2STRIDE + lane]);
      float g2 = bf2f(h2b[(size_t)(c2.x & 0x1FFFF) * H2STRIDE + lane]);
      float g3 = bf2f(h2b[(size_t)(c3.x & 0x1FFFF) * H2STRIDE + lane]);
      acc += __int_as_float(c0.y) * g0;
      acc += __int_as_float(c1.y) * g1;
      acc += __int_as_float(c2.y) * g2;
      acc += __int_as_float(c3.y) * g3;
    }
    for (; e < ee; ++e) {
      int2 c0 = eS[e];
      acc += __int_as_float(c0.y) * bf2f(h2b[(size_t)(c0.x & 0x1FFFF) * H2STRIDE + lane]);
    }
    float m = (lane < C_OUT) ? acc : -INFINITY;
    #pragma unroll
    for (int o = 32; o > 0; o >>= 1) m = fmaxf(m, __shfl_xor(m, o));
    float ev = (lane < C_OUT) ? __expf(acc - m) : 0.f;
    float s = ev;
    #pragma unroll
    for (int o = 32; o > 0; o >>= 1) s += __shfl_xor(s, o);
    if (lane < C_OUT) out[(long)row * C_OUT + lane] = acc - m - __logf(s);
  }
}

extern "C" void kernel_launch(void* const* d_in, const int* in_sizes, int n_in,
                              void* d_out, int out_size, void* d_ws, size_t ws_size,
                              hipStream_t stream) {
  const float* x    = (const float*)d_in[0];
  const float* W1   = (const float*)d_in[1];
  const float* b1   = (const float*)d_in[2];
  const float* W2   = (const float*)d_in[3];
  const float* b2   = (const float*)d_in[4];
  const int*   erow = (const int*)d_in[5];
  const int*   ecol = (const int*)d_in[6];
  const float* eval = (const float*)d_in[7];
  const int E  = in_sizes[5];
  const int CH = (E + NCH - 1) / NCH;

  // ws: h2b 12.8MB | W1S 256KB | W2T 24KB | offs 2MB | bsums 1KB |
  //     bstart 6.3KB | sorted E*8B (~34 MB)
  char* p = (char*)d_ws;
  short* h2b    = (short*)p;  p += (size_t)N_NODES * H2STRIDE * 2;
  short* W1S    = (short*)p;  p += (size_t)16*256*32 * 2;
  short* W2T    = (short*)p;  p += (size_t)48*256 * 2;
  int*   offs   = (int*)p;    p += (size_t)SCAN_M * 4;
  int*   bsums  = (int*)p;    p += 256 * 4;
  int*   bstart = (int*)p;    p += (size_t)(NBUCK + 4) * 4;
  int2*  sorted = (int2*)p;
  float* out = (float*)d_out;

  k_pack_weights<<<(16*256*32 + 48*256 + 255)/256, 256, 0, stream>>>(W1, W2, W1S, W2T);
  k_fused_mlp<<<(N_NODES + 127)/128, 512, 0, stream>>>(x, b1, b2, W1S, W2T, h2b);
  k_hist2<<<NCH, 256, 0, stream>>>(erow, offs, E, CH);
  k_scan1<<<NBS, 256, 0, stream>>>(offs, bsums);
  k_split<<<NCH, 256, 0, stream>>>(erow, ecol, eval, offs, bsums, sorted, bstart, E, CH);
  k_csr_spmm<<<NBUCK, 256, 0, stream>>>(bstart, sorted, h2b, out);
}

// Round 8
// 505.626 us; speedup vs baseline: 2.2417x; 1.0453x over previous
//
#include <hip/hip_runtime.h>
#include <hip/hip_bf16.h>

// LSAPPNP: h = relu(x@W1+b1); h2 = h@W2+b2; agg[r] += val*h2[c] over edges;
// out = log_softmax(0.1*h2 + agg, axis=1)
// N=100000, F_IN=500, HID=256, C=40, E~2.3M
//
// Round 14: edge-kernel parallelism/ILP. R13 best (528.5) but 391us sits
// in 4 edge kernels that are latency-bound, not traffic-bound:
// hist2/split at 320 blocks (1.25/CU) with scalar loads; csr_spmm gather
// only 4-deep. Changes: NCH=1024 (4 blocks/CU), int4/float4 edge loads
// (4 edges/vmem), scan2 restored (tiny), csr_spmm 8-deep gather unroll.
// MLP byte-identical R8 (128.8us measured).

#define N_NODES 100000
#define F_IN    500
#define HID     256
#define C_OUT   40
#define ALPHA0  0.1f
#define H2STRIDE 64

#define RPB     64                            // rows per bucket
#define NBUCK   ((N_NODES + RPB - 1) / RPB)   // 1563
#define NCH     1024                          // edge chunks (hist/split blocks)
#define SCAN_M  (NBUCK * NCH)                 // 1600512
#define SCAN_CHUNK 2048
#define NBS     ((SCAN_M + SCAN_CHUNK - 1) / SCAN_CHUNK)  // 782
#define BCAPL   1792                          // bucket cap (mean 1474, +8.3 sigma)

typedef short short8 __attribute__((ext_vector_type(8)));
typedef float f32x4  __attribute__((ext_vector_type(4)));

__device__ __forceinline__ short f2bf(float f) {
  union { float f; unsigned u; } x; x.f = f;
  unsigned r = x.u + 0x7fffu + ((x.u >> 16) & 1u);  // RNE
  return (short)(r >> 16);
}
__device__ __forceinline__ float bf2f(short s) {
  union { unsigned u; float f; } x; x.u = ((unsigned)(unsigned short)s) << 16;
  return x.f;
}
// packed f32x2 -> bf16x2 (RNE), single VOP3
__device__ __forceinline__ unsigned cvtpk(float lo, float hi) {
  unsigned r;
  asm("v_cvt_pk_bf16_f32 %0, %1, %2" : "=v"(r) : "v"(lo), "v"(hi));
  return r;
}
// LDS-only barrier: drain DS ops, then raw s_barrier (no vmcnt drain).
__device__ __forceinline__ void lbar() {
  asm volatile("s_waitcnt lgkmcnt(0)" ::: "memory");
  __builtin_amdgcn_s_barrier();
}
// async global->LDS, 16B per lane; LDS dest = wave-uniform base + lane*16
__device__ __forceinline__ void gll16(const float* g, const char* l) {
  __builtin_amdgcn_global_load_lds(
      (const __attribute__((address_space(1))) void*)g,
      (__attribute__((address_space(3))) void*)l, 16, 0, 0);
}

// ---- K0: pack W1 -> W1S [16 kc][256 n][32 k] bf16; W2 -> W2T [48 n][256 k]
__global__ __launch_bounds__(256) void k_pack_weights(
    const float* __restrict__ W1, const float* __restrict__ W2,
    short* __restrict__ W1S, short* __restrict__ W2T)
{
  int i = blockIdx.x * 256 + threadIdx.x;
  if (i < 16*256*32) {
    int kc  = i >> 13;
    int idx = i & 8191;
    int n   = idx >> 5;
    int kk  = idx & 31;
    int k   = kc*32 + kk;
    float v = (k < F_IN) ? W1[k*HID + n] : 0.f;
    W1S[i] = f2bf(v);
  } else {
    int j = i - 16*256*32;
    if (j < 48*256) {
      int n = j >> 8;
      int k = j & 255;
      float v = (n < C_OUT) ? W2[k*C_OUT + n] : 0.f;
      W2T[j] = f2bf(v);
    }
  }
}

// ---- K1: fused MLP (R8 structure: gll f32 staging, counted vmcnt, no full
// syncthreads in K loop). 512 thr = 8 waves (2 row x 4 col), tile 128x256.
__global__ __launch_bounds__(512, 4) void k_fused_mlp(
    const float* __restrict__ x, const float* __restrict__ b1v,
    const float* __restrict__ b2v,
    const short* __restrict__ W1S, const short* __restrict__ W2T,
    short* __restrict__ h2b)
{
  __shared__ __align__(16) char smem[65536];
  short (*Hl)[256] = (short(*)[256])smem;   // post-loop overlay, 64KB

  const int tid  = threadIdx.x;
  const int w    = tid >> 6;
  const int lane = tid & 63;
  const int lr   = lane & 15;
  const int quad = lane >> 4;
  const int wr   = w >> 2;      // 0..1 row-wave
  const int wc   = w & 3;       // 0..3 col-wave
  const int row0 = blockIdx.x * 128;

  const int s_rl0 = (w*2)*8 + (lane>>3);
  const int s_rl1 = (w*2+1)*8 + (lane>>3);
  const int ksw   = ((lane&7) ^ ((lane>>3)&7)) * 4;
  const float* gp0 = x + (size_t)min(row0 + s_rl0, N_NODES-1) * F_IN;
  const float* gp1 = x + (size_t)min(row0 + s_rl1, N_NODES-1) * F_IN;
  const char* l0 = smem + (w*2)*1024;       // + buf*16384
  const char* l1 = smem + (w*2+1)*1024;

  f32x4 acc[4][4] = {};

  #pragma unroll
  for (int p = 0; p < 2; ++p) {
    int kb = p*32 + ksw;
    const float* a0 = (kb + 4 <= F_IN) ? gp0 + kb : x;
    const float* a1 = (kb + 4 <= F_IN) ? gp1 + kb : x;
    gll16(a0, l0 + p*16384);
    gll16(a1, l1 + p*16384);
  }

  const short* bbase = W1S + (wc*64 + lr)*32 + quad*8;
  const int m2 = lr & 7;

  #pragma unroll
  for (int kc = 0; kc < 16; ++kc) {
    short8 bf4[4];
    #pragma unroll
    for (int t = 0; t < 4; ++t)
      bf4[t] = *(const short8*)(bbase + kc*8192 + t*16*32);
    __builtin_amdgcn_sched_barrier(0);

    if (kc < 14) {
      int kb = (kc+2)*32 + ksw;
      const float* a0 = (kb + 4 <= F_IN) ? gp0 + kb : x;
      const float* a1 = (kb + 4 <= F_IN) ? gp1 + kb : x;
      gll16(a0, l0 + ((kc+2)&3)*16384);
      gll16(a1, l1 + ((kc+2)&3)*16384);
      __builtin_amdgcn_sched_barrier(0);
      asm volatile("s_waitcnt vmcnt(8)" ::: "memory");
    } else if (kc == 14) {
      asm volatile("s_waitcnt vmcnt(6)" ::: "memory");
    } else {
      asm volatile("s_waitcnt vmcnt(4)" ::: "memory");
    }
    __builtin_amdgcn_s_barrier();

    const char* Abase = smem + (kc & 3)*16384;
    short8 af[4];
    #pragma unroll
    for (int t = 0; t < 4; ++t) {
      int rl = wr*64 + t*16 + lr;
      f32x4 u0 = *(const f32x4*)(Abase + rl*128 + (((quad*2  ) ^ m2) << 4));
      f32x4 u1 = *(const f32x4*)(Abase + rl*128 + (((quad*2+1) ^ m2) << 4));
      union { unsigned u[4]; short8 s; } pk;
      pk.u[0] = cvtpk(u0[0], u0[1]);
      pk.u[1] = cvtpk(u0[2], u0[3]);
      pk.u[2] = cvtpk(u1[0], u1[1]);
      pk.u[3] = cvtpk(u1[2], u1[3]);
      af[t] = pk.s;
    }

    #pragma unroll
    for (int rt = 0; rt < 4; ++rt)
      #pragma unroll
      for (int ct = 0; ct < 4; ++ct)
        acc[rt][ct] = __builtin_amdgcn_mfma_f32_16x16x32_bf16(af[rt], bf4[ct], acc[rt][ct], 0, 0, 0);
  }
  lbar();

  #pragma unroll
  for (int ct = 0; ct < 4; ++ct) {
    int col = wc*64 + ct*16 + lr;
    int cg = col >> 3, ci = col & 7;
    float bias = b1v[col];
    #pragma unroll
    for (int rt = 0; rt < 4; ++rt) {
      #pragma unroll
      for (int r = 0; r < 4; ++r) {
        int row = wr*64 + rt*16 + quad*4 + r;
        float v = fmaxf(acc[rt][ct][r] + bias, 0.f);
        Hl[row][((cg ^ (row & 31)) << 3) | ci] = f2bf(v);
      }
    }
  }
  lbar();

  f32x4 acc2[3] = {};
  const int arow = w*16 + lr;
  #pragma unroll
  for (int kc2 = 0; kc2 < 8; ++kc2) {
    int gg = kc2*4 + quad;
    short8 a2 = *(const short8*)&Hl[arow][(gg ^ (arow & 31)) << 3];
    #pragma unroll
    for (int nt = 0; nt < 3; ++nt) {
      short8 b2 = *(const short8*)(W2T + (nt*16 + lr)*256 + kc2*32 + quad*8);
      acc2[nt] = __builtin_amdgcn_mfma_f32_16x16x32_bf16(a2, b2, acc2[nt], 0, 0, 0);
    }
  }

  #pragma unroll
  for (int nt = 0; nt < 3; ++nt) {
    int col = nt*16 + lr;
    float bias = (col < C_OUT) ? b2v[col] : 0.f;
    #pragma unroll
    for (int r = 0; r < 4; ++r) {
      int row = row0 + w*16 + quad*4 + r;
      if (row < N_NODES) {
        float v = (col < C_OUT) ? (acc2[nt][r] + bias) : 0.f;
        h2b[(long)row * H2STRIDE + col] = f2bf(v);
      }
    }
  }
  {
    int col = 48 + lr;
    #pragma unroll
    for (int r = 0; r < 4; ++r) {
      int row = row0 + w*16 + quad*4 + r;
      if (row < N_NODES) h2b[(long)row * H2STRIDE + col] = 0;
    }
  }
}

// ---- K2: per-chunk LDS histogram of buckets (row>>6), int4 edge loads.
__global__ __launch_bounds__(256) void k_hist2(
    const int* __restrict__ erow, int* __restrict__ offs, int E, int CH)
{
  __shared__ int h[NBUCK];
  int tid = threadIdx.x, c = blockIdx.x;
  for (int b = tid; b < NBUCK; b += 256) h[b] = 0;
  __syncthreads();
  int e0 = c * CH, e1 = min(E, e0 + CH);   // e0 multiple of 4 (CH rounded)
  if (e0 < e1) {
    int g0 = e0 >> 2, g1 = e1 >> 2;
    const int4* rp = (const int4*)erow;
    for (int g = g0 + tid; g < g1; g += 256) {
      int4 r4 = rp[g];
      atomicAdd(&h[r4.x >> 6], 1);
      atomicAdd(&h[r4.y >> 6], 1);
      atomicAdd(&h[r4.z >> 6], 1);
      atomicAdd(&h[r4.w >> 6], 1);
    }
    for (int e = (g1 << 2) + tid; e < e1; e += 256)
      atomicAdd(&h[erow[e] >> 6], 1);
  }
  __syncthreads();
  for (int b = tid; b < NBUCK; b += 256) offs[b * NCH + c] = h[b];
}

// ---- K3a: scan phase 1 — 2048-elem chunks, in-place exclusive scan + sums
__global__ __launch_bounds__(256) void k_scan1(
    int* __restrict__ offs, int* __restrict__ bsums)
{
  __shared__ int sh[256];
  int tid = threadIdx.x;
  int base = blockIdx.x * SCAN_CHUNK + tid * 8;
  int d[8];
  #pragma unroll
  for (int k = 0; k < 8; ++k)
    d[k] = (base + k < SCAN_M) ? offs[base + k] : 0;
  int s = 0;
  #pragma unroll
  for (int k = 0; k < 8; ++k) s += d[k];
  sh[tid] = s;
  __syncthreads();
  for (int o = 1; o < 256; o <<= 1) {
    int v = (tid >= o) ? sh[tid - o] : 0;
    __syncthreads();
    if (tid >= o) sh[tid] += v;
    __syncthreads();
  }
  int run = sh[tid] - s;
  #pragma unroll
  for (int k = 0; k < 8; ++k) {
    if (base + k < SCAN_M) offs[base + k] = run;
    run += d[k];
  }
  if (tid == 255) bsums[blockIdx.x] = sh[255];
}

// ---- K3b: scan phase 2 — exclusive scan of NBS (782) block sums, 1 block.
__global__ __launch_bounds__(256) void k_scan2(int* __restrict__ bsums) {
  __shared__ int sh[256];
  int tid = threadIdx.x;
  int d[4];
  int s = 0;
  #pragma unroll
  for (int k = 0; k < 4; ++k) {
    int i = tid * 4 + k;
    d[k] = (i < NBS) ? bsums[i] : 0;
    s += d[k];
  }
  sh[tid] = s;
  __syncthreads();
  for (int o = 1; o < 256; o <<= 1) {
    int u = (tid >= o) ? sh[tid - o] : 0;
    __syncthreads();
    if (tid >= o) sh[tid] += u;
    __syncthreads();
  }
  int run = sh[tid] - s;
  #pragma unroll
  for (int k = 0; k < 4; ++k) {
    int i = tid * 4 + k;
    if (i < NBS) bsums[i] = run;
    run += d[k];
  }
}

// ---- K4: split edges into bucket-grouped order (LDS cursors, int4 loads).
// cur[b] = offs[b*NCH+c] + bsums_scanned[(b*NCH+c)>>11]. Block 0 emits bstart.
__global__ __launch_bounds__(256) void k_split(
    const int* __restrict__ erow, const int* __restrict__ ecol,
    const float* __restrict__ eval, const int* __restrict__ offs,
    const int* __restrict__ bsums, int2* __restrict__ sorted,
    int* __restrict__ bstart, int E, int CH)
{
  __shared__ int cur[NBUCK];
  int tid = threadIdx.x, c = blockIdx.x;

  for (int b = tid; b < NBUCK; b += 256) {
    int m = b * NCH + c;
    int val = offs[m] + bsums[m >> 11];
    cur[b] = val;
    if (c == 0) bstart[b] = val;
  }
  if (c == 0 && tid == 0) bstart[NBUCK] = E;
  __syncthreads();

  int e0 = c * CH, e1 = min(E, e0 + CH);
  if (e0 >= e1) return;
  int g0 = e0 >> 2, g1 = e1 >> 2;
  const int4*   rp = (const int4*)erow;
  const int4*   cp = (const int4*)ecol;
  const float4* vp = (const float4*)eval;
  for (int g = g0 + tid; g < g1; g += 256) {
    int4 r4 = rp[g];
    int4 c4 = cp[g];
    float4 v4 = vp[g];
    int p0 = atomicAdd(&cur[r4.x >> 6], 1);
    int p1 = atomicAdd(&cur[r4.y >> 6], 1);
    int p2 = atomicAdd(&cur[r4.z >> 6], 1);
    int p3 = atomicAdd(&cur[r4.w >> 6], 1);
    int2 cv;
    cv.x = c4.x | ((r4.x & 63) << 17); cv.y = __float_as_int(v4.x); sorted[p0] = cv;
    cv.x = c4.y | ((r4.y & 63) << 17); cv.y = __float_as_int(v4.y); sorted[p1] = cv;
    cv.x = c4.z | ((r4.z & 63) << 17); cv.y = __float_as_int(v4.z); sorted[p2] = cv;
    cv.x = c4.w | ((r4.w & 63) << 17); cv.y = __float_as_int(v4.w); sorted[p3] = cv;
  }
  for (int e = (g1 << 2) + tid; e < e1; e += 256) {
    int r = erow[e];
    int pos = atomicAdd(&cur[r >> 6], 1);
    int2 cv;
    cv.x = ecol[e] | ((r & 63) << 17);
    cv.y = __float_as_int(eval[e]);
    sorted[pos] = cv;
  }
}

// ---- K5: fused per-bucket CSR sort (in LDS) + wave-per-row SpMM + softmax.
// One block (4 waves) per 64-row bucket; 8-deep gather pipeline.
__global__ __launch_bounds__(256) void k_csr_spmm(
    const int* __restrict__ bstart, const int2* __restrict__ sorted,
    const short* __restrict__ h2b, float* __restrict__ out)
{
  __shared__ int2 eS[BCAPL];      // 14336 B
  __shared__ int h[RPB];
  __shared__ int roff[RPB];       // inclusive scan
  __shared__ int cur[RPB];
  int tid = threadIdx.x, b = blockIdx.x;
  int lane = tid & 63, w = tid >> 6;
  int start = bstart[b], end = bstart[b + 1];
  int cnt = end - start;

  // stage bucket edges into registers (<= 7 per thread)
  int2 cv[7];
  int nloc = 0;
  for (int i = tid, k = 0; i < cnt; i += 256, ++k) { cv[k] = sorted[start + i]; nloc = k + 1; }

  if (tid < RPB) h[tid] = 0;
  __syncthreads();
  for (int k = 0; k < nloc; ++k)
    atomicAdd(&h[((unsigned)cv[k].x) >> 17], 1);
  __syncthreads();
  if (tid < RPB) roff[tid] = h[tid];
  __syncthreads();
  for (int o = 1; o < RPB; o <<= 1) {
    int u = (tid >= o && tid < RPB) ? roff[tid - o] : 0;
    __syncthreads();
    if (tid >= o && tid < RPB) roff[tid] += u;
    __syncthreads();
  }
  if (tid < RPB) cur[tid] = roff[tid] - h[tid];   // exclusive start
  __syncthreads();
  for (int k = 0; k < nloc; ++k) {
    unsigned rl = ((unsigned)cv[k].x) >> 17;
    int p = atomicAdd(&cur[rl], 1);
    if (p < BCAPL) eS[p] = cv[k];
  }
  __syncthreads();

  // SpMM: wave w handles rows w*16 .. +15, 8-deep gather pipeline
  for (int rr = 0; rr < 16; ++rr) {
    int r = w * 16 + rr;
    int row = b * RPB + r;
    if (row >= N_NODES) continue;
    float acc = ALPHA0 * bf2f(h2b[(size_t)row * H2STRIDE + lane]);  // 0 for lane>=40
    int e  = roff[r] - h[r];
    int ee = roff[r];
    for (; e + 7 < ee; e += 8) {
      int2 cc[8];
      float gg[8];
      #pragma unroll
      for (int j = 0; j < 8; ++j) cc[j] = eS[e + j];
      #pragma unroll
      for (int j = 0; j < 8; ++j)
        gg[j] = bf2f(h2b[(size_t)(cc[j].x & 0x1FFFF) * H2STRIDE + lane]);
      #pragma unroll
      for (int j = 0; j < 8; ++j) acc += __int_as_float(cc[j].y) * gg[j];
    }
    for (; e + 3 < ee; e += 4) {
      int2 c0 = eS[e], c1 = eS[e+1], c2 = eS[e+2], c3 = eS[e+3];
      float g0 = bf2f(h2b[(size_t)(c0.x & 0x1FFFF) * H2STRIDE + lane]);
      float g1 = bf2f(h2b[(size_t)(c1.x & 0x1FFFF) * H2STRIDE + lane]);
      float g2 = bf2f(h2b[(size_t)(c2.x & 0x1FFFF) * H2STRIDE + lane]);
      float g3 = bf2f(h2b[(size_t)(c3.x & 0x1FFFF) * H2STRIDE + lane]);
      acc += __int_as_float(c0.y) * g0;
      acc += __int_as_float(c1.y) * g1;
      acc += __int_as_float(c2.y) * g2;
      acc += __int_as_float(c3.y) * g3;
    }
    for (; e < ee; ++e) {
      int2 c0 = eS[e];
      acc += __int_as_float(c0.y) * bf2f(h2b[(size_t)(c0.x & 0x1FFFF) * H2STRIDE + lane]);
    }
    float m = (lane < C_OUT) ? acc : -INFINITY;
    #pragma unroll
    for (int o = 32; o > 0; o >>= 1) m = fmaxf(m, __shfl_xor(m, o));
    float ev = (lane < C_OUT) ? __expf(acc - m) : 0.f;
    float s = ev;
    #pragma unroll
    for (int o = 32; o > 0; o >>= 1) s += __shfl_xor(s, o);
    if (lane < C_OUT) out[(long)row * C_OUT + lane] = acc - m - __logf(s);
  }
}

extern "C" void kernel_launch(void* const* d_in, const int* in_sizes, int n_in,
                              void* d_out, int out_size, void* d_ws, size_t ws_size,
                              hipStream_t stream) {
  const float* x    = (const float*)d_in[0];
  const float* W1   = (const float*)d_in[1];
  const float* b1   = (const float*)d_in[2];
  const float* W2   = (const float*)d_in[3];
  const float* b2   = (const float*)d_in[4];
  const int*   erow = (const int*)d_in[5];
  const int*   ecol = (const int*)d_in[6];
  const float* eval = (const float*)d_in[7];
  const int E  = in_sizes[5];
  int CH = (E + NCH - 1) / NCH;
  CH = (CH + 3) & ~3;                 // multiple of 4 for int4 alignment

  // ws: h2b 12.8MB | W1S 256KB | W2T 24KB | offs 6.4MB | bsums 4KB |
  //     bstart 6.3KB | sorted E*8B (~38 MB)
  char* p = (char*)d_ws;
  short* h2b    = (short*)p;  p += (size_t)N_NODES * H2STRIDE * 2;
  short* W1S    = (short*)p;  p += (size_t)16*256*32 * 2;
  short* W2T    = (short*)p;  p += (size_t)48*256 * 2;
  int*   offs   = (int*)p;    p += (size_t)SCAN_M * 4;
  int*   bsums  = (int*)p;    p += 1024 * 4;
  int*   bstart = (int*)p;    p += (size_t)(NBUCK + 4) * 4;
  int2*  sorted = (int2*)p;
  float* out = (float*)d_out;

  k_pack_weights<<<(16*256*32 + 48*256 + 255)/256, 256, 0, stream>>>(W1, W2, W1S, W2T);
  k_fused_mlp<<<(N_NODES + 127)/128, 512, 0, stream>>>(x, b1, b2, W1S, W2T, h2b);
  k_hist2<<<NCH, 256, 0, stream>>>(erow, offs, E, CH);
  k_scan1<<<NBS, 256, 0, stream>>>(offs, bsums);
  k_scan2<<<1, 256, 0, stream>>>(bsums);
  k_split<<<NCH, 256, 0, stream>>>(erow, ecol, eval, offs, bsums, sorted, bstart, E, CH);
  k_csr_spmm<<<NBUCK, 256, 0, stream>>>(bstart, sorted, h2b, out);
}

// Round 9
// 502.336 us; speedup vs baseline: 2.2563x; 1.0065x over previous
//
#include <hip/hip_runtime.h>
#include <hip/hip_bf16.h>

// LSAPPNP: h = relu(x@W1+b1); h2 = h@W2+b2; agg[r] += val*h2[c] over edges;
// out = log_softmax(0.1*h2 + agg, axis=1)
// N=100000, F_IN=500, HID=256, C=40, E~2.3M
//
// Round 15: hist folded into MLP (post-phase, overlaps MLP latency; one
// fewer dispatch) + staging transpose to kill offs write-amplification
// (hist wrote offs[b*NCH+c] at stride 4KB -> 32 writer-blocks per 128B
// line; now hist writes hs[c][b] coalesced, 400-block LDS transpose
// produces offs[b][c]). scan/split/csr unchanged from R14 (505.6us).

#define N_NODES 100000
#define F_IN    500
#define HID     256
#define C_OUT   40
#define ALPHA0  0.1f
#define H2STRIDE 64

#define RPB     64                            // rows per bucket
#define NBUCK   ((N_NODES + RPB - 1) / RPB)   // 1563
#define NBUCKP  1568                          // padded (x32)
#define NCH     1024                          // edge chunks
#define SCAN_M  (NBUCK * NCH)                 // 1600512
#define SCAN_CHUNK 2048
#define NBS     ((SCAN_M + SCAN_CHUNK - 1) / SCAN_CHUNK)  // 782
#define BCAPL   1792                          // bucket cap (mean 1474, +8.3 sigma)

typedef short short8 __attribute__((ext_vector_type(8)));
typedef float f32x4  __attribute__((ext_vector_type(4)));

__device__ __forceinline__ short f2bf(float f) {
  union { float f; unsigned u; } x; x.f = f;
  unsigned r = x.u + 0x7fffu + ((x.u >> 16) & 1u);  // RNE
  return (short)(r >> 16);
}
__device__ __forceinline__ float bf2f(short s) {
  union { unsigned u; float f; } x; x.u = ((unsigned)(unsigned short)s) << 16;
  return x.f;
}
// packed f32x2 -> bf16x2 (RNE), single VOP3
__device__ __forceinline__ unsigned cvtpk(float lo, float hi) {
  unsigned r;
  asm("v_cvt_pk_bf16_f32 %0, %1, %2" : "=v"(r) : "v"(lo), "v"(hi));
  return r;
}
// LDS-only barrier: drain DS ops, then raw s_barrier (no vmcnt drain).
__device__ __forceinline__ void lbar() {
  asm volatile("s_waitcnt lgkmcnt(0)" ::: "memory");
  __builtin_amdgcn_s_barrier();
}
// async global->LDS, 16B per lane; LDS dest = wave-uniform base + lane*16
__device__ __forceinline__ void gll16(const float* g, const char* l) {
  __builtin_amdgcn_global_load_lds(
      (const __attribute__((address_space(1))) void*)g,
      (__attribute__((address_space(3))) void*)l, 16, 0, 0);
}

// ---- K0: pack W1 -> W1S [16 kc][256 n][32 k] bf16; W2 -> W2T [48 n][256 k]
__global__ __launch_bounds__(256) void k_pack_weights(
    const float* __restrict__ W1, const float* __restrict__ W2,
    short* __restrict__ W1S, short* __restrict__ W2T)
{
  int i = blockIdx.x * 256 + threadIdx.x;
  if (i < 16*256*32) {
    int kc  = i >> 13;
    int idx = i & 8191;
    int n   = idx >> 5;
    int kk  = idx & 31;
    int k   = kc*32 + kk;
    float v = (k < F_IN) ? W1[k*HID + n] : 0.f;
    W1S[i] = f2bf(v);
  } else {
    int j = i - 16*256*32;
    if (j < 48*256) {
      int n = j >> 8;
      int k = j & 255;
      float v = (n < C_OUT) ? W2[k*C_OUT + n] : 0.f;
      W2T[j] = f2bf(v);
    }
  }
}

// ---- K1: fused MLP (R8 structure) + folded edge histogram post-phase.
// 512 thr = 8 waves (2 row x 4 col), tile 128x256. After the MLP epilogue,
// each block histograms edge chunks bid, bid+782 into LDS and writes
// hs[c][b] COALESCED (staging; transposed later). Overlaps MLP latency.
__global__ __launch_bounds__(512, 4) void k_fused_mlp(
    const float* __restrict__ x, const float* __restrict__ b1v,
    const float* __restrict__ b2v,
    const short* __restrict__ W1S, const short* __restrict__ W2T,
    short* __restrict__ h2b,
    const int* __restrict__ erow, int* __restrict__ hs, int E, int CH)
{
  __shared__ __align__(16) char smem[65536];
  short (*Hl)[256] = (short(*)[256])smem;   // post-loop overlay, 64KB

  const int tid  = threadIdx.x;
  const int w    = tid >> 6;
  const int lane = tid & 63;
  const int lr   = lane & 15;
  const int quad = lane >> 4;
  const int wr   = w >> 2;      // 0..1 row-wave
  const int wc   = w & 3;       // 0..3 col-wave
  const int row0 = blockIdx.x * 128;

  const int s_rl0 = (w*2)*8 + (lane>>3);
  const int s_rl1 = (w*2+1)*8 + (lane>>3);
  const int ksw   = ((lane&7) ^ ((lane>>3)&7)) * 4;
  const float* gp0 = x + (size_t)min(row0 + s_rl0, N_NODES-1) * F_IN;
  const float* gp1 = x + (size_t)min(row0 + s_rl1, N_NODES-1) * F_IN;
  const char* l0 = smem + (w*2)*1024;       // + buf*16384
  const char* l1 = smem + (w*2+1)*1024;

  f32x4 acc[4][4] = {};

  #pragma unroll
  for (int p = 0; p < 2; ++p) {
    int kb = p*32 + ksw;
    const float* a0 = (kb + 4 <= F_IN) ? gp0 + kb : x;
    const float* a1 = (kb + 4 <= F_IN) ? gp1 + kb : x;
    gll16(a0, l0 + p*16384);
    gll16(a1, l1 + p*16384);
  }

  const short* bbase = W1S + (wc*64 + lr)*32 + quad*8;
  const int m2 = lr & 7;

  #pragma unroll
  for (int kc = 0; kc < 16; ++kc) {
    short8 bf4[4];
    #pragma unroll
    for (int t = 0; t < 4; ++t)
      bf4[t] = *(const short8*)(bbase + kc*8192 + t*16*32);
    __builtin_amdgcn_sched_barrier(0);

    if (kc < 14) {
      int kb = (kc+2)*32 + ksw;
      const float* a0 = (kb + 4 <= F_IN) ? gp0 + kb : x;
      const float* a1 = (kb + 4 <= F_IN) ? gp1 + kb : x;
      gll16(a0, l0 + ((kc+2)&3)*16384);
      gll16(a1, l1 + ((kc+2)&3)*16384);
      __builtin_amdgcn_sched_barrier(0);
      asm volatile("s_waitcnt vmcnt(8)" ::: "memory");
    } else if (kc == 14) {
      asm volatile("s_waitcnt vmcnt(6)" ::: "memory");
    } else {
      asm volatile("s_waitcnt vmcnt(4)" ::: "memory");
    }
    __builtin_amdgcn_s_barrier();

    const char* Abase = smem + (kc & 3)*16384;
    short8 af[4];
    #pragma unroll
    for (int t = 0; t < 4; ++t) {
      int rl = wr*64 + t*16 + lr;
      f32x4 u0 = *(const f32x4*)(Abase + rl*128 + (((quad*2  ) ^ m2) << 4));
      f32x4 u1 = *(const f32x4*)(Abase + rl*128 + (((quad*2+1) ^ m2) << 4));
      union { unsigned u[4]; short8 s; } pk;
      pk.u[0] = cvtpk(u0[0], u0[1]);
      pk.u[1] = cvtpk(u0[2], u0[3]);
      pk.u[2] = cvtpk(u1[0], u1[1]);
      pk.u[3] = cvtpk(u1[2], u1[3]);
      af[t] = pk.s;
    }

    #pragma unroll
    for (int rt = 0; rt < 4; ++rt)
      #pragma unroll
      for (int ct = 0; ct < 4; ++ct)
        acc[rt][ct] = __builtin_amdgcn_mfma_f32_16x16x32_bf16(af[rt], bf4[ct], acc[rt][ct], 0, 0, 0);
  }
  lbar();

  #pragma unroll
  for (int ct = 0; ct < 4; ++ct) {
    int col = wc*64 + ct*16 + lr;
    int cg = col >> 3, ci = col & 7;
    float bias = b1v[col];
    #pragma unroll
    for (int rt = 0; rt < 4; ++rt) {
      #pragma unroll
      for (int r = 0; r < 4; ++r) {
        int row = wr*64 + rt*16 + quad*4 + r;
        float v = fmaxf(acc[rt][ct][r] + bias, 0.f);
        Hl[row][((cg ^ (row & 31)) << 3) | ci] = f2bf(v);
      }
    }
  }
  lbar();

  f32x4 acc2[3] = {};
  const int arow = w*16 + lr;
  #pragma unroll
  for (int kc2 = 0; kc2 < 8; ++kc2) {
    int gg = kc2*4 + quad;
    short8 a2 = *(const short8*)&Hl[arow][(gg ^ (arow & 31)) << 3];
    #pragma unroll
    for (int nt = 0; nt < 3; ++nt) {
      short8 b2 = *(const short8*)(W2T + (nt*16 + lr)*256 + kc2*32 + quad*8);
      acc2[nt] = __builtin_amdgcn_mfma_f32_16x16x32_bf16(a2, b2, acc2[nt], 0, 0, 0);
    }
  }

  #pragma unroll
  for (int nt = 0; nt < 3; ++nt) {
    int col = nt*16 + lr;
    float bias = (col < C_OUT) ? b2v[col] : 0.f;
    #pragma unroll
    for (int r = 0; r < 4; ++r) {
      int row = row0 + w*16 + quad*4 + r;
      if (row < N_NODES) {
        float v = (col < C_OUT) ? (acc2[nt][r] + bias) : 0.f;
        h2b[(long)row * H2STRIDE + col] = f2bf(v);
      }
    }
  }
  {
    int col = 48 + lr;
    #pragma unroll
    for (int r = 0; r < 4; ++r) {
      int row = row0 + w*16 + quad*4 + r;
      if (row < N_NODES) h2b[(long)row * H2STRIDE + col] = 0;
    }
  }

  // ---- folded hist phase: chunks bid, bid+gridDim ----
  int* hcnt = (int*)smem;   // 1563 ints; Hl dead after lbar below
  for (int cc = blockIdx.x; cc < NCH; cc += gridDim.x) {
    lbar();                                   // all Hl reads drained
    for (int b = tid; b < NBUCK; b += 512) hcnt[b] = 0;
    __syncthreads();
    int e0 = cc * CH, e1 = min(E, e0 + CH);   // e0 multiple of 4
    if (e0 < e1) {
      int g0 = e0 >> 2, g1 = e1 >> 2;
      const int4* rp = (const int4*)erow;
      for (int g = g0 + tid; g < g1; g += 512) {
        int4 r4 = rp[g];
        atomicAdd(&hcnt[r4.x >> 6], 1);
        atomicAdd(&hcnt[r4.y >> 6], 1);
        atomicAdd(&hcnt[r4.z >> 6], 1);
        atomicAdd(&hcnt[r4.w >> 6], 1);
      }
      for (int e = (g1 << 2) + tid; e < e1; e += 512)
        atomicAdd(&hcnt[erow[e] >> 6], 1);
    }
    __syncthreads();
    for (int b = tid; b < NBUCK; b += 512)
      hs[(size_t)cc * NBUCKP + b] = hcnt[b];  // coalesced staging write
  }
}

// ---- K2: transpose hs[c][b] -> offs[b][c]. 64x64 LDS tiles, both sides
// coalesced (kills the stride-4KB scatter-write amplification).
__global__ __launch_bounds__(256) void k_transpose(
    const int* __restrict__ hs, int* __restrict__ offs)
{
  __shared__ int t[64][65];
  int cb = blockIdx.x & 15;          // chunk tile (NCH/64 = 16)
  int bb = blockIdx.x >> 4;          // bucket tile (25)
  int c0 = cb * 64, b0 = bb * 64;
  int j  = threadIdx.x & 63;
  int i0 = threadIdx.x >> 6;
  #pragma unroll
  for (int k = 0; k < 16; ++k) {
    int i = i0 + k * 4;              // chunk offset
    int b = b0 + j;
    t[i][j] = (b < NBUCK) ? hs[(size_t)(c0 + i) * NBUCKP + b] : 0;
  }
  __syncthreads();
  #pragma unroll
  for (int k = 0; k < 16; ++k) {
    int i = i0 + k * 4;              // bucket offset
    int b = b0 + i;
    if (b < NBUCK) offs[(size_t)b * NCH + c0 + j] = t[j][i];
  }
}

// ---- K3a: scan phase 1 — 2048-elem chunks, in-place exclusive scan + sums
__global__ __launch_bounds__(256) void k_scan1(
    int* __restrict__ offs, int* __restrict__ bsums)
{
  __shared__ int sh[256];
  int tid = threadIdx.x;
  int base = blockIdx.x * SCAN_CHUNK + tid * 8;
  int d[8];
  #pragma unroll
  for (int k = 0; k < 8; ++k)
    d[k] = (base + k < SCAN_M) ? offs[base + k] : 0;
  int s = 0;
  #pragma unroll
  for (int k = 0; k < 8; ++k) s += d[k];
  sh[tid] = s;
  __syncthreads();
  for (int o = 1; o < 256; o <<= 1) {
    int v = (tid >= o) ? sh[tid - o] : 0;
    __syncthreads();
    if (tid >= o) sh[tid] += v;
    __syncthreads();
  }
  int run = sh[tid] - s;
  #pragma unroll
  for (int k = 0; k < 8; ++k) {
    if (base + k < SCAN_M) offs[base + k] = run;
    run += d[k];
  }
  if (tid == 255) bsums[blockIdx.x] = sh[255];
}

// ---- K3b: scan phase 2 — exclusive scan of NBS (782) block sums, 1 block.
__global__ __launch_bounds__(256) void k_scan2(int* __restrict__ bsums) {
  __shared__ int sh[256];
  int tid = threadIdx.x;
  int d[4];
  int s = 0;
  #pragma unroll
  for (int k = 0; k < 4; ++k) {
    int i = tid * 4 + k;
    d[k] = (i < NBS) ? bsums[i] : 0;
    s += d[k];
  }
  sh[tid] = s;
  __syncthreads();
  for (int o = 1; o < 256; o <<= 1) {
    int u = (tid >= o) ? sh[tid - o] : 0;
    __syncthreads();
    if (tid >= o) sh[tid] += u;
    __syncthreads();
  }
  int run = sh[tid] - s;
  #pragma unroll
  for (int k = 0; k < 4; ++k) {
    int i = tid * 4 + k;
    if (i < NBS) bsums[i] = run;
    run += d[k];
  }
}

// ---- K4: split edges into bucket-grouped order (LDS cursors, int4 loads).
// cur[b] = offs[b*NCH+c] + bsums_scanned[(b*NCH+c)>>11]. Block 0 emits bstart.
__global__ __launch_bounds__(256) void k_split(
    const int* __restrict__ erow, const int* __restrict__ ecol,
    const float* __restrict__ eval, const int* __restrict__ offs,
    const int* __restrict__ bsums, int2* __restrict__ sorted,
    int* __restrict__ bstart, int E, int CH)
{
  __shared__ int cur[NBUCK];
  int tid = threadIdx.x, c = blockIdx.x;

  for (int b = tid; b < NBUCK; b += 256) {
    int m = b * NCH + c;
    int val = offs[m] + bsums[m >> 11];
    cur[b] = val;
    if (c == 0) bstart[b] = val;
  }
  if (c == 0 && tid == 0) bstart[NBUCK] = E;
  __syncthreads();

  int e0 = c * CH, e1 = min(E, e0 + CH);
  if (e0 >= e1) return;
  int g0 = e0 >> 2, g1 = e1 >> 2;
  const int4*   rp = (const int4*)erow;
  const int4*   cp = (const int4*)ecol;
  const float4* vp = (const float4*)eval;
  for (int g = g0 + tid; g < g1; g += 256) {
    int4 r4 = rp[g];
    int4 c4 = cp[g];
    float4 v4 = vp[g];
    int p0 = atomicAdd(&cur[r4.x >> 6], 1);
    int p1 = atomicAdd(&cur[r4.y >> 6], 1);
    int p2 = atomicAdd(&cur[r4.z >> 6], 1);
    int p3 = atomicAdd(&cur[r4.w >> 6], 1);
    int2 cv;
    cv.x = c4.x | ((r4.x & 63) << 17); cv.y = __float_as_int(v4.x); sorted[p0] = cv;
    cv.x = c4.y | ((r4.y & 63) << 17); cv.y = __float_as_int(v4.y); sorted[p1] = cv;
    cv.x = c4.z | ((r4.z & 63) << 17); cv.y = __float_as_int(v4.z); sorted[p2] = cv;
    cv.x = c4.w | ((r4.w & 63) << 17); cv.y = __float_as_int(v4.w); sorted[p3] = cv;
  }
  for (int e = (g1 << 2) + tid; e < e1; e += 256) {
    int r = erow[e];
    int pos = atomicAdd(&cur[r >> 6], 1);
    int2 cv;
    cv.x = ecol[e] | ((r & 63) << 17);
    cv.y = __float_as_int(eval[e]);
    sorted[pos] = cv;
  }
}

// ---- K5: fused per-bucket CSR sort (in LDS) + wave-per-row SpMM + softmax.
// One block (4 waves) per 64-row bucket; 8-deep gather pipeline.
__global__ __launch_bounds__(256) void k_csr_spmm(
    const int* __restrict__ bstart, const int2* __restrict__ sorted,
    const short* __restrict__ h2b, float* __restrict__ out)
{
  __shared__ int2 eS[BCAPL];      // 14336 B
  __shared__ int h[RPB];
  __shared__ int roff[RPB];       // inclusive scan
  __shared__ int cur[RPB];
  int tid = threadIdx.x, b = blockIdx.x;
  int lane = tid & 63, w = tid >> 6;
  int start = bstart[b], end = bstart[b + 1];
  int cnt = end - start;

  // stage bucket edges into registers (<= 7 per thread)
  int2 cv[7];
  int nloc = 0;
  for (int i = tid, k = 0; i < cnt; i += 256, ++k) { cv[k] = sorted[start + i]; nloc = k + 1; }

  if (tid < RPB) h[tid] = 0;
  __syncthreads();
  for (int k = 0; k < nloc; ++k)
    atomicAdd(&h[((unsigned)cv[k].x) >> 17], 1);
  __syncthreads();
  if (tid < RPB) roff[tid] = h[tid];
  __syncthreads();
  for (int o = 1; o < RPB; o <<= 1) {
    int u = (tid >= o && tid < RPB) ? roff[tid - o] : 0;
    __syncthreads();
    if (tid >= o && tid < RPB) roff[tid] += u;
    __syncthreads();
  }
  if (tid < RPB) cur[tid] = roff[tid] - h[tid];   // exclusive start
  __syncthreads();
  for (int k = 0; k < nloc; ++k) {
    unsigned rl = ((unsigned)cv[k].x) >> 17;
    int p = atomicAdd(&cur[rl], 1);
    if (p < BCAPL) eS[p] = cv[k];
  }
  __syncthreads();

  // SpMM: wave w handles rows w*16 .. +15, 8-deep gather pipeline
  for (int rr = 0; rr < 16; ++rr) {
    int r = w * 16 + rr;
    int row = b * RPB + r;
    if (row >= N_NODES) continue;
    float acc = ALPHA0 * bf2f(h2b[(size_t)row * H2STRIDE + lane]);  // 0 for lane>=40
    int e  = roff[r] - h[r];
    int ee = roff[r];
    for (; e + 7 < ee; e += 8) {
      int2 cc[8];
      float gg[8];
      #pragma unroll
      for (int j = 0; j < 8; ++j) cc[j] = eS[e + j];
      #pragma unroll
      for (int j = 0; j < 8; ++j)
        gg[j] = bf2f(h2b[(size_t)(cc[j].x & 0x1FFFF) * H2STRIDE + lane]);
      #pragma unroll
      for (int j = 0; j < 8; ++j) acc += __int_as_float(cc[j].y) * gg[j];
    }
    for (; e + 3 < ee; e += 4) {
      int2 c0 = eS[e], c1 = eS[e+1], c2 = eS[e+2], c3 = eS[e+3];
      float g0 = bf2f(h2b[(size_t)(c0.x & 0x1FFFF) * H2STRIDE + lane]);
      float g1 = bf2f(h2b[(size_t)(c1.x & 0x1FFFF) * H2STRIDE + lane]);
      float g2 = bf2f(h2b[(size_t)(c2.x & 0x1FFFF) * H2STRIDE + lane]);
      float g3 = bf2f(h2b[(size_t)(c3.x & 0x1FFFF) * H2STRIDE + lane]);
      acc += __int_as_float(c0.y) * g0;
      acc += __int_as_float(c1.y) * g1;
      acc += __int_as_float(c2.y) * g2;
      acc += __int_as_float(c3.y) * g3;
    }
    for (; e < ee; ++e) {
      int2 c0 = eS[e];
      acc += __int_as_float(c0.y) * bf2f(h2b[(size_t)(c0.x & 0x1FFFF) * H2STRIDE + lane]);
    }
    float m = (lane < C_OUT) ? acc : -INFINITY;
    #pragma unroll
    for (int o = 32; o > 0; o >>= 1) m = fmaxf(m, __shfl_xor(m, o));
    float ev = (lane < C_OUT) ? __expf(acc - m) : 0.f;
    float s = ev;
    #pragma unroll
    for (int o = 32; o > 0; o >>= 1) s += __shfl_xor(s, o);
    if (lane < C_OUT) out[(long)row * C_OUT + lane] = acc - m - __logf(s);
  }
}

extern "C" void kernel_launch(void* const* d_in, const int* in_sizes, int n_in,
                              void* d_out, int out_size, void* d_ws, size_t ws_size,
                              hipStream_t stream) {
  const float* x    = (const float*)d_in[0];
  const float* W1   = (const float*)d_in[1];
  const float* b1   = (const float*)d_in[2];
  const float* W2   = (const float*)d_in[3];
  const float* b2   = (const float*)d_in[4];
  const int*   erow = (const int*)d_in[5];
  const int*   ecol = (const int*)d_in[6];
  const float* eval = (const float*)d_in[7];
  const int E  = in_sizes[5];
  int CH = (E + NCH - 1) / NCH;
  CH = (CH + 3) & ~3;                 // multiple of 4 for int4 alignment

  // ws: h2b 12.8MB | W1S 256KB | W2T 24KB | hs 6.4MB | offs 6.4MB |
  //     bsums 4KB | bstart 6.3KB | sorted E*8B (~45 MB)
  char* p = (char*)d_ws;
  short* h2b    = (short*)p;  p += (size_t)N_NODES * H2STRIDE * 2;
  short* W1S    = (short*)p;  p += (size_t)16*256*32 * 2;
  short* W2T    = (short*)p;  p += (size_t)48*256 * 2;
  int*   hs     = (int*)p;    p += (size_t)NCH * NBUCKP * 4;
  int*   offs   = (int*)p;    p += (size_t)SCAN_M * 4;
  int*   bsums  = (int*)p;    p += 1024 * 4;
  int*   bstart = (int*)p;    p += (size_t)(NBUCK + 4) * 4;
  int2*  sorted = (int2*)p;
  float* out = (float*)d_out;

  k_pack_weights<<<(16*256*32 + 48*256 + 255)/256, 256, 0, stream>>>(W1, W2, W1S, W2T);
  k_fused_mlp<<<(N_NODES + 127)/128, 512, 0, stream>>>(x, b1, b2, W1S, W2T, h2b,
                                                       erow, hs, E, CH);
  k_transpose<<<16 * 25, 256, 0, stream>>>(hs, offs);
  k_scan1<<<NBS, 256, 0, stream>>>(offs, bsums);
  k_scan2<<<1, 256, 0, stream>>>(bsums);
  k_split<<<NCH, 256, 0, stream>>>(erow, ecol, eval, offs, bsums, sorted, bstart, E, CH);
  k_csr_spmm<<<NBUCK, 256, 0, stream>>>(bstart, sorted, h2b, out);
}

// Round 10
// 478.790 us; speedup vs baseline: 2.3673x; 1.0492x over previous
//
#include <hip/hip_runtime.h>
#include <hip/hip_bf16.h>

// LSAPPNP: h = relu(x@W1+b1); h2 = h@W2+b2; agg[r] += val*h2[c] over edges;
// out = log_softmax(0.1*h2 + agg, axis=1)
// N=100000, F_IN=500, HID=256, C=40, E~2.3M
//
// Round 16: (1) csr_spmm de-scratch — the int2 cv[7] runtime-indexed stage
// spilled to scratch (VGPR=24, occupancy 3.5%, 177us); replaced by two
// coalesced passes over sorted + wave-0 shfl scan (3 barriers). (2) split
// write-amp fix: NCH 1024->256 @512thr (segments 46B, amp ~2.8x vs 16x).
// (3) scan shrinks 4x. MLP core unchanged (R8 structure).

#define N_NODES 100000
#define F_IN    500
#define HID     256
#define C_OUT   40
#define ALPHA0  0.1f
#define H2STRIDE 64

#define RPB     64                            // rows per bucket
#define NBUCK   ((N_NODES + RPB - 1) / RPB)   // 1563
#define NBUCKP  1568                          // padded (x32)
#define NCH     256                           // edge chunks
#define SCAN_M  (NBUCK * NCH)                 // 400128
#define SCAN_CHUNK 2048
#define NBS     ((SCAN_M + SCAN_CHUNK - 1) / SCAN_CHUNK)  // 196
#define BCAPL   1792                          // bucket cap (mean 1474, +8.3 sigma)

typedef short short8 __attribute__((ext_vector_type(8)));
typedef float f32x4  __attribute__((ext_vector_type(4)));

__device__ __forceinline__ short f2bf(float f) {
  union { float f; unsigned u; } x; x.f = f;
  unsigned r = x.u + 0x7fffu + ((x.u >> 16) & 1u);  // RNE
  return (short)(r >> 16);
}
__device__ __forceinline__ float bf2f(short s) {
  union { unsigned u; float f; } x; x.u = ((unsigned)(unsigned short)s) << 16;
  return x.f;
}
// packed f32x2 -> bf16x2 (RNE), single VOP3
__device__ __forceinline__ unsigned cvtpk(float lo, float hi) {
  unsigned r;
  asm("v_cvt_pk_bf16_f32 %0, %1, %2" : "=v"(r) : "v"(lo), "v"(hi));
  return r;
}
// LDS-only barrier: drain DS ops, then raw s_barrier (no vmcnt drain).
__device__ __forceinline__ void lbar() {
  asm volatile("s_waitcnt lgkmcnt(0)" ::: "memory");
  __builtin_amdgcn_s_barrier();
}
// async global->LDS, 16B per lane; LDS dest = wave-uniform base + lane*16
__device__ __forceinline__ void gll16(const float* g, const char* l) {
  __builtin_amdgcn_global_load_lds(
      (const __attribute__((address_space(1))) void*)g,
      (__attribute__((address_space(3))) void*)l, 16, 0, 0);
}

// ---- K0: pack W1 -> W1S [16 kc][256 n][32 k] bf16; W2 -> W2T [48 n][256 k]
__global__ __launch_bounds__(256) void k_pack_weights(
    const float* __restrict__ W1, const float* __restrict__ W2,
    short* __restrict__ W1S, short* __restrict__ W2T)
{
  int i = blockIdx.x * 256 + threadIdx.x;
  if (i < 16*256*32) {
    int kc  = i >> 13;
    int idx = i & 8191;
    int n   = idx >> 5;
    int kk  = idx & 31;
    int k   = kc*32 + kk;
    float v = (k < F_IN) ? W1[k*HID + n] : 0.f;
    W1S[i] = f2bf(v);
  } else {
    int j = i - 16*256*32;
    if (j < 48*256) {
      int n = j >> 8;
      int k = j & 255;
      float v = (n < C_OUT) ? W2[k*C_OUT + n] : 0.f;
      W2T[j] = f2bf(v);
    }
  }
}

// ---- K1: fused MLP (R8 structure) + folded edge histogram post-phase.
// Blocks 0..NCH-1 histogram one ~9K-edge chunk each after the MLP epilogue
// (they are dispatched first -> hist overlaps later MLP rounds).
__global__ __launch_bounds__(512, 4) void k_fused_mlp(
    const float* __restrict__ x, const float* __restrict__ b1v,
    const float* __restrict__ b2v,
    const short* __restrict__ W1S, const short* __restrict__ W2T,
    short* __restrict__ h2b,
    const int* __restrict__ erow, int* __restrict__ hs, int E, int CH)
{
  __shared__ __align__(16) char smem[65536];
  short (*Hl)[256] = (short(*)[256])smem;   // post-loop overlay, 64KB

  const int tid  = threadIdx.x;
  const int w    = tid >> 6;
  const int lane = tid & 63;
  const int lr   = lane & 15;
  const int quad = lane >> 4;
  const int wr   = w >> 2;      // 0..1 row-wave
  const int wc   = w & 3;       // 0..3 col-wave
  const int row0 = blockIdx.x * 128;

  const int s_rl0 = (w*2)*8 + (lane>>3);
  const int s_rl1 = (w*2+1)*8 + (lane>>3);
  const int ksw   = ((lane&7) ^ ((lane>>3)&7)) * 4;
  const float* gp0 = x + (size_t)min(row0 + s_rl0, N_NODES-1) * F_IN;
  const float* gp1 = x + (size_t)min(row0 + s_rl1, N_NODES-1) * F_IN;
  const char* l0 = smem + (w*2)*1024;       // + buf*16384
  const char* l1 = smem + (w*2+1)*1024;

  f32x4 acc[4][4] = {};

  #pragma unroll
  for (int p = 0; p < 2; ++p) {
    int kb = p*32 + ksw;
    const float* a0 = (kb + 4 <= F_IN) ? gp0 + kb : x;
    const float* a1 = (kb + 4 <= F_IN) ? gp1 + kb : x;
    gll16(a0, l0 + p*16384);
    gll16(a1, l1 + p*16384);
  }

  const short* bbase = W1S + (wc*64 + lr)*32 + quad*8;
  const int m2 = lr & 7;

  #pragma unroll
  for (int kc = 0; kc < 16; ++kc) {
    short8 bf4[4];
    #pragma unroll
    for (int t = 0; t < 4; ++t)
      bf4[t] = *(const short8*)(bbase + kc*8192 + t*16*32);
    __builtin_amdgcn_sched_barrier(0);

    if (kc < 14) {
      int kb = (kc+2)*32 + ksw;
      const float* a0 = (kb + 4 <= F_IN) ? gp0 + kb : x;
      const float* a1 = (kb + 4 <= F_IN) ? gp1 + kb : x;
      gll16(a0, l0 + ((kc+2)&3)*16384);
      gll16(a1, l1 + ((kc+2)&3)*16384);
      __builtin_amdgcn_sched_barrier(0);
      asm volatile("s_waitcnt vmcnt(8)" ::: "memory");
    } else if (kc == 14) {
      asm volatile("s_waitcnt vmcnt(6)" ::: "memory");
    } else {
      asm volatile("s_waitcnt vmcnt(4)" ::: "memory");
    }
    __builtin_amdgcn_s_barrier();

    const char* Abase = smem + (kc & 3)*16384;
    short8 af[4];
    #pragma unroll
    for (int t = 0; t < 4; ++t) {
      int rl = wr*64 + t*16 + lr;
      f32x4 u0 = *(const f32x4*)(Abase + rl*128 + (((quad*2  ) ^ m2) << 4));
      f32x4 u1 = *(const f32x4*)(Abase + rl*128 + (((quad*2+1) ^ m2) << 4));
      union { unsigned u[4]; short8 s; } pk;
      pk.u[0] = cvtpk(u0[0], u0[1]);
      pk.u[1] = cvtpk(u0[2], u0[3]);
      pk.u[2] = cvtpk(u1[0], u1[1]);
      pk.u[3] = cvtpk(u1[2], u1[3]);
      af[t] = pk.s;
    }

    #pragma unroll
    for (int rt = 0; rt < 4; ++rt)
      #pragma unroll
      for (int ct = 0; ct < 4; ++ct)
        acc[rt][ct] = __builtin_amdgcn_mfma_f32_16x16x32_bf16(af[rt], bf4[ct], acc[rt][ct], 0, 0, 0);
  }
  lbar();

  #pragma unroll
  for (int ct = 0; ct < 4; ++ct) {
    int col = wc*64 + ct*16 + lr;
    int cg = col >> 3, ci = col & 7;
    float bias = b1v[col];
    #pragma unroll
    for (int rt = 0; rt < 4; ++rt) {
      #pragma unroll
      for (int r = 0; r < 4; ++r) {
        int row = wr*64 + rt*16 + quad*4 + r;
        float v = fmaxf(acc[rt][ct][r] + bias, 0.f);
        Hl[row][((cg ^ (row & 31)) << 3) | ci] = f2bf(v);
      }
    }
  }
  lbar();

  f32x4 acc2[3] = {};
  const int arow = w*16 + lr;
  #pragma unroll
  for (int kc2 = 0; kc2 < 8; ++kc2) {
    int gg = kc2*4 + quad;
    short8 a2 = *(const short8*)&Hl[arow][(gg ^ (arow & 31)) << 3];
    #pragma unroll
    for (int nt = 0; nt < 3; ++nt) {
      short8 b2 = *(const short8*)(W2T + (nt*16 + lr)*256 + kc2*32 + quad*8);
      acc2[nt] = __builtin_amdgcn_mfma_f32_16x16x32_bf16(a2, b2, acc2[nt], 0, 0, 0);
    }
  }

  #pragma unroll
  for (int nt = 0; nt < 3; ++nt) {
    int col = nt*16 + lr;
    float bias = (col < C_OUT) ? b2v[col] : 0.f;
    #pragma unroll
    for (int r = 0; r < 4; ++r) {
      int row = row0 + w*16 + quad*4 + r;
      if (row < N_NODES) {
        float v = (col < C_OUT) ? (acc2[nt][r] + bias) : 0.f;
        h2b[(long)row * H2STRIDE + col] = f2bf(v);
      }
    }
  }
  {
    int col = 48 + lr;
    #pragma unroll
    for (int r = 0; r < 4; ++r) {
      int row = row0 + w*16 + quad*4 + r;
      if (row < N_NODES) h2b[(long)row * H2STRIDE + col] = 0;
    }
  }

  // ---- folded hist phase: block bid handles chunk bid (bid < NCH) ----
  if (blockIdx.x < NCH) {
    int cc = blockIdx.x;
    int* hcnt = (int*)smem;   // 1563 ints; Hl dead after lbar
    lbar();
    for (int b = tid; b < NBUCK; b += 512) hcnt[b] = 0;
    __syncthreads();
    int e0 = cc * CH, e1 = min(E, e0 + CH);   // e0 multiple of 4
    if (e0 < e1) {
      int g0 = e0 >> 2, g1 = e1 >> 2;
      const int4* rp = (const int4*)erow;
      for (int g = g0 + tid; g < g1; g += 512) {
        int4 r4 = rp[g];
        atomicAdd(&hcnt[r4.x >> 6], 1);
        atomicAdd(&hcnt[r4.y >> 6], 1);
        atomicAdd(&hcnt[r4.z >> 6], 1);
        atomicAdd(&hcnt[r4.w >> 6], 1);
      }
      for (int e = (g1 << 2) + tid; e < e1; e += 512)
        atomicAdd(&hcnt[erow[e] >> 6], 1);
    }
    __syncthreads();
    for (int b = tid; b < NBUCK; b += 512)
      hs[(size_t)cc * NBUCKP + b] = hcnt[b];  // coalesced staging write
  }
}

// ---- K2: transpose hs[c][b] -> offs[b][c]. 64x64 LDS tiles, both coalesced.
__global__ __launch_bounds__(256) void k_transpose(
    const int* __restrict__ hs, int* __restrict__ offs)
{
  __shared__ int t[64][65];
  int cb = blockIdx.x & 3;           // chunk tile (NCH/64 = 4)
  int bb = blockIdx.x >> 2;          // bucket tile (25)
  int c0 = cb * 64, b0 = bb * 64;
  int j  = threadIdx.x & 63;
  int i0 = threadIdx.x >> 6;
  #pragma unroll
  for (int k = 0; k < 16; ++k) {
    int i = i0 + k * 4;              // chunk offset
    int b = b0 + j;
    t[i][j] = (b < NBUCK) ? hs[(size_t)(c0 + i) * NBUCKP + b] : 0;
  }
  __syncthreads();
  #pragma unroll
  for (int k = 0; k < 16; ++k) {
    int i = i0 + k * 4;              // bucket offset
    int b = b0 + i;
    if (b < NBUCK) offs[(size_t)b * NCH + c0 + j] = t[j][i];
  }
}

// ---- K3a: scan phase 1 — 2048-elem chunks, in-place exclusive scan + sums
__global__ __launch_bounds__(256) void k_scan1(
    int* __restrict__ offs, int* __restrict__ bsums)
{
  __shared__ int sh[256];
  int tid = threadIdx.x;
  int base = blockIdx.x * SCAN_CHUNK + tid * 8;
  int d[8];
  #pragma unroll
  for (int k = 0; k < 8; ++k)
    d[k] = (base + k < SCAN_M) ? offs[base + k] : 0;
  int s = 0;
  #pragma unroll
  for (int k = 0; k < 8; ++k) s += d[k];
  sh[tid] = s;
  __syncthreads();
  for (int o = 1; o < 256; o <<= 1) {
    int v = (tid >= o) ? sh[tid - o] : 0;
    __syncthreads();
    if (tid >= o) sh[tid] += v;
    __syncthreads();
  }
  int run = sh[tid] - s;
  #pragma unroll
  for (int k = 0; k < 8; ++k) {
    if (base + k < SCAN_M) offs[base + k] = run;
    run += d[k];
  }
  if (tid == 255) bsums[blockIdx.x] = sh[255];
}

// ---- K3b: scan phase 2 — exclusive scan of NBS (196) block sums, 1 block.
__global__ __launch_bounds__(256) void k_scan2(int* __restrict__ bsums) {
  __shared__ int sh[256];
  int tid = threadIdx.x;
  int v = (tid < NBS) ? bsums[tid] : 0;
  sh[tid] = v;
  __syncthreads();
  for (int o = 1; o < 256; o <<= 1) {
    int u = (tid >= o) ? sh[tid - o] : 0;
    __syncthreads();
    if (tid >= o) sh[tid] += u;
    __syncthreads();
  }
  if (tid < NBS) bsums[tid] = sh[tid] - v;
}

// ---- K4: split edges into bucket-grouped order (LDS cursors, int4 loads,
// 512 thr). cur[b] = offs[b*NCH+c] + bsums[(b*NCH+c)>>11]. Block 0 -> bstart.
__global__ __launch_bounds__(512) void k_split(
    const int* __restrict__ erow, const int* __restrict__ ecol,
    const float* __restrict__ eval, const int* __restrict__ offs,
    const int* __restrict__ bsums, int2* __restrict__ sorted,
    int* __restrict__ bstart, int E, int CH)
{
  __shared__ int cur[NBUCK];
  int tid = threadIdx.x, c = blockIdx.x;

  for (int b = tid; b < NBUCK; b += 512) {
    int m = b * NCH + c;
    int val = offs[m] + bsums[m >> 11];
    cur[b] = val;
    if (c == 0) bstart[b] = val;
  }
  if (c == 0 && tid == 0) bstart[NBUCK] = E;
  __syncthreads();

  int e0 = c * CH, e1 = min(E, e0 + CH);
  if (e0 >= e1) return;
  int g0 = e0 >> 2, g1 = e1 >> 2;
  const int4*   rp = (const int4*)erow;
  const int4*   cp = (const int4*)ecol;
  const float4* vp = (const float4*)eval;
  for (int g = g0 + tid; g < g1; g += 512) {
    int4 r4 = rp[g];
    int4 c4 = cp[g];
    float4 v4 = vp[g];
    int p0 = atomicAdd(&cur[r4.x >> 6], 1);
    int p1 = atomicAdd(&cur[r4.y >> 6], 1);
    int p2 = atomicAdd(&cur[r4.z >> 6], 1);
    int p3 = atomicAdd(&cur[r4.w >> 6], 1);
    int2 cv;
    cv.x = c4.x | ((r4.x & 63) << 17); cv.y = __float_as_int(v4.x); sorted[p0] = cv;
    cv.x = c4.y | ((r4.y & 63) << 17); cv.y = __float_as_int(v4.y); sorted[p1] = cv;
    cv.x = c4.z | ((r4.z & 63) << 17); cv.y = __float_as_int(v4.z); sorted[p2] = cv;
    cv.x = c4.w | ((r4.w & 63) << 17); cv.y = __float_as_int(v4.w); sorted[p3] = cv;
  }
  for (int e = (g1 << 2) + tid; e < e1; e += 512) {
    int r = erow[e];
    int pos = atomicAdd(&cur[r >> 6], 1);
    int2 cv;
    cv.x = ecol[e] | ((r & 63) << 17);
    cv.y = __float_as_int(eval[e]);
    sorted[pos] = cv;
  }
}

// ---- K5: fused per-bucket CSR sort (in LDS) + wave-per-row SpMM + softmax.
// Two coalesced passes over sorted (NO register staging -> no scratch).
// Wave-0 shfl scan (RPB=64 = one wave). 3 barriers total before SpMM.
__global__ __launch_bounds__(256) void k_csr_spmm(
    const int* __restrict__ bstart, const int2* __restrict__ sorted,
    const short* __restrict__ h2b, float* __restrict__ out)
{
  __shared__ int2 eS[BCAPL];      // 14336 B
  __shared__ int h[RPB];
  __shared__ int roff[RPB];       // inclusive scan
  __shared__ int cur[RPB];
  int tid = threadIdx.x, b = blockIdx.x;
  int lane = tid & 63, w = tid >> 6;
  int start = bstart[b], end = bstart[b + 1];
  int cnt = end - start;

  if (tid < RPB) h[tid] = 0;
  __syncthreads();
  // pass 1: histogram (coalesced read)
  for (int i = tid; i < cnt; i += 256)
    atomicAdd(&h[((unsigned)sorted[start + i].x) >> 17], 1);
  __syncthreads();
  // wave-0 inclusive shfl scan over 64 counts
  if (w == 0) {
    int v = h[lane];
    int hv = v;
    #pragma unroll
    for (int o = 1; o < 64; o <<= 1) {
      int t = __shfl_up(v, o);
      if (lane >= o) v += t;
    }
    roff[lane] = v;
    cur[lane]  = v - hv;    // exclusive start
  }
  __syncthreads();
  // pass 2: scatter into LDS row-sorted order
  for (int i = tid; i < cnt; i += 256) {
    int2 cv = sorted[start + i];
    int p = atomicAdd(&cur[((unsigned)cv.x) >> 17], 1);
    if (p < BCAPL) eS[p] = cv;
  }
  __syncthreads();

  // SpMM: wave w handles rows w*16 .. +15, 8-deep gather pipeline
  for (int rr = 0; rr < 16; ++rr) {
    int r = w * 16 + rr;
    int row = b * RPB + r;
    if (row >= N_NODES) continue;
    float acc = ALPHA0 * bf2f(h2b[(size_t)row * H2STRIDE + lane]);  // 0 for lane>=40
    int e  = roff[r] - h[r];
    int ee = roff[r];
    for (; e + 7 < ee; e += 8) {
      int2 cc[8];
      float gg[8];
      #pragma unroll
      for (int j = 0; j < 8; ++j) cc[j] = eS[e + j];
      #pragma unroll
      for (int j = 0; j < 8; ++j)
        gg[j] = bf2f(h2b[(size_t)(cc[j].x & 0x1FFFF) * H2STRIDE + lane]);
      #pragma unroll
      for (int j = 0; j < 8; ++j) acc += __int_as_float(cc[j].y) * gg[j];
    }
    for (; e + 3 < ee; e += 4) {
      int2 c0 = eS[e], c1 = eS[e+1], c2 = eS[e+2], c3 = eS[e+3];
      float g0 = bf2f(h2b[(size_t)(c0.x & 0x1FFFF) * H2STRIDE + lane]);
      float g1 = bf2f(h2b[(size_t)(c1.x & 0x1FFFF) * H2STRIDE + lane]);
      float g2 = bf2f(h2b[(size_t)(c2.x & 0x1FFFF) * H2STRIDE + lane]);
      float g3 = bf2f(h2b[(size_t)(c3.x & 0x1FFFF) * H2STRIDE + lane]);
      acc += __int_as_float(c0.y) * g0;
      acc += __int_as_float(c1.y) * g1;
      acc += __int_as_float(c2.y) * g2;
      acc += __int_as_float(c3.y) * g3;
    }
    for (; e < ee; ++e) {
      int2 c0 = eS[e];
      acc += __int_as_float(c0.y) * bf2f(h2b[(size_t)(c0.x & 0x1FFFF) * H2STRIDE + lane]);
    }
    float m = (lane < C_OUT) ? acc : -INFINITY;
    #pragma unroll
    for (int o = 32; o > 0; o >>= 1) m = fmaxf(m, __shfl_xor(m, o));
    float ev = (lane < C_OUT) ? __expf(acc - m) : 0.f;
    float s = ev;
    #pragma unroll
    for (int o = 32; o > 0; o >>= 1) s += __shfl_xor(s, o);
    if (lane < C_OUT) out[(long)row * C_OUT + lane] = acc - m - __logf(s);
  }
}

extern "C" void kernel_launch(void* const* d_in, const int* in_sizes, int n_in,
                              void* d_out, int out_size, void* d_ws, size_t ws_size,
                              hipStream_t stream) {
  const float* x    = (const float*)d_in[0];
  const float* W1   = (const float*)d_in[1];
  const float* b1   = (const float*)d_in[2];
  const float* W2   = (const float*)d_in[3];
  const float* b2   = (const float*)d_in[4];
  const int*   erow = (const int*)d_in[5];
  const int*   ecol = (const int*)d_in[6];
  const float* eval = (const float*)d_in[7];
  const int E  = in_sizes[5];
  int CH = (E + NCH - 1) / NCH;
  CH = (CH + 3) & ~3;                 // multiple of 4 for int4 alignment

  // ws: h2b 12.8MB | W1S 256KB | W2T 24KB | hs 1.6MB | offs 1.6MB |
  //     bsums 1KB | bstart 6.3KB | sorted E*8B (~35 MB)
  char* p = (char*)d_ws;
  short* h2b    = (short*)p;  p += (size_t)N_NODES * H2STRIDE * 2;
  short* W1S    = (short*)p;  p += (size_t)16*256*32 * 2;
  short* W2T    = (short*)p;  p += (size_t)48*256 * 2;
  int*   hs     = (int*)p;    p += (size_t)NCH * NBUCKP * 4;
  int*   offs   = (int*)p;    p += (size_t)SCAN_M * 4;
  int*   bsums  = (int*)p;    p += 256 * 4;
  int*   bstart = (int*)p;    p += (size_t)(NBUCK + 4) * 4;
  int2*  sorted = (int2*)p;
  float* out = (float*)d_out;

  k_pack_weights<<<(16*256*32 + 48*256 + 255)/256, 256, 0, stream>>>(W1, W2, W1S, W2T);
  k_fused_mlp<<<(N_NODES + 127)/128, 512, 0, stream>>>(x, b1, b2, W1S, W2T, h2b,
                                                       erow, hs, E, CH);
  k_transpose<<<4 * 25, 256, 0, stream>>>(hs, offs);
  k_scan1<<<NBS, 256, 0, stream>>>(offs, bsums);
  k_scan2<<<1, 256, 0, stream>>>(bsums);
  k_split<<<NCH, 512, 0, stream>>>(erow, ecol, eval, offs, bsums, sorted, bstart, E, CH);
  k_csr_spmm<<<NBUCK, 256, 0, stream>>>(bstart, sorted, h2b, out);
}

// Round 11
// 463.185 us; speedup vs baseline: 2.4471x; 1.0337x over previous
//
#include <hip/hip_runtime.h>
#include <hip/hip_bf16.h>

// LSAPPNP: h = relu(x@W1+b1); h2 = h@W2+b2; agg[r] += val*h2[c] over edges;
// out = log_softmax(0.1*h2 + agg, axis=1)
// N=100000, F_IN=500, HID=256, C=40, E~2.3M
//
// Round 17: chunk-major sorted layout. Split writes ONLY into its own
// contiguous CH*8B window (open write lines fit L2 -> write amp ~1),
// using per-chunk bucket prefixes lofs[c][b] computed by a block scan
// folded into the MLP hist phase -> global 400K scan (scan1+scan2)
// DELETED. csr_spmm assembles its bucket from 256 per-chunk segments
// (lofsT rows b,b+1 coalesced; hist fused into segment copy; ONE global
// pass over sorted instead of two), 512 thr for gather latency hiding.
// 7 launches -> 5. MLP core unchanged (R8 structure).

#define N_NODES 100000
#define F_IN    500
#define HID     256
#define C_OUT   40
#define ALPHA0  0.1f
#define H2STRIDE 64

#define RPB     64                            // rows per bucket
#define NBUCK   ((N_NODES + RPB - 1) / RPB)   // 1563
#define NBUCKP  1568                          // padded (x32, >= NBUCK+1)
#define NCH     256                           // edge chunks
#define BCAPL   1792                          // bucket cap (mean 1474, +8.3 sigma)

typedef short short8 __attribute__((ext_vector_type(8)));
typedef float f32x4  __attribute__((ext_vector_type(4)));

__device__ __forceinline__ short f2bf(float f) {
  union { float f; unsigned u; } x; x.f = f;
  unsigned r = x.u + 0x7fffu + ((x.u >> 16) & 1u);  // RNE
  return (short)(r >> 16);
}
__device__ __forceinline__ float bf2f(short s) {
  union { unsigned u; float f; } x; x.u = ((unsigned)(unsigned short)s) << 16;
  return x.f;
}
// packed f32x2 -> bf16x2 (RNE), single VOP3
__device__ __forceinline__ unsigned cvtpk(float lo, float hi) {
  unsigned r;
  asm("v_cvt_pk_bf16_f32 %0, %1, %2" : "=v"(r) : "v"(lo), "v"(hi));
  return r;
}
// LDS-only barrier: drain DS ops, then raw s_barrier (no vmcnt drain).
__device__ __forceinline__ void lbar() {
  asm volatile("s_waitcnt lgkmcnt(0)" ::: "memory");
  __builtin_amdgcn_s_barrier();
}
// async global->LDS, 16B per lane; LDS dest = wave-uniform base + lane*16
__device__ __forceinline__ void gll16(const float* g, const char* l) {
  __builtin_amdgcn_global_load_lds(
      (const __attribute__((address_space(1))) void*)g,
      (__attribute__((address_space(3))) void*)l, 16, 0, 0);
}

// ---- K0: pack W1 -> W1S [16 kc][256 n][32 k] bf16; W2 -> W2T [48 n][256 k]
__global__ __launch_bounds__(256) void k_pack_weights(
    const float* __restrict__ W1, const float* __restrict__ W2,
    short* __restrict__ W1S, short* __restrict__ W2T)
{
  int i = blockIdx.x * 256 + threadIdx.x;
  if (i < 16*256*32) {
    int kc  = i >> 13;
    int idx = i & 8191;
    int n   = idx >> 5;
    int kk  = idx & 31;
    int k   = kc*32 + kk;
    float v = (k < F_IN) ? W1[k*HID + n] : 0.f;
    W1S[i] = f2bf(v);
  } else {
    int j = i - 16*256*32;
    if (j < 48*256) {
      int n = j >> 8;
      int k = j & 255;
      float v = (n < C_OUT) ? W2[k*C_OUT + n] : 0.f;
      W2T[j] = f2bf(v);
    }
  }
}

// ---- K1: fused MLP (R8 structure) + folded hist+scan post-phase.
// Blocks 0..NCH-1: histogram one chunk into LDS, block-scan the 1568
// counts, write lofs[c][b] (exclusive per-chunk prefix; [NBUCK] = total).
__global__ __launch_bounds__(512, 4) void k_fused_mlp(
    const float* __restrict__ x, const float* __restrict__ b1v,
    const float* __restrict__ b2v,
    const short* __restrict__ W1S, const short* __restrict__ W2T,
    short* __restrict__ h2b,
    const int* __restrict__ erow, int* __restrict__ lofs, int E, int CH)
{
  __shared__ __align__(16) char smem[65536];
  short (*Hl)[256] = (short(*)[256])smem;   // post-loop overlay, 64KB

  const int tid  = threadIdx.x;
  const int w    = tid >> 6;
  const int lane = tid & 63;
  const int lr   = lane & 15;
  const int quad = lane >> 4;
  const int wr   = w >> 2;      // 0..1 row-wave
  const int wc   = w & 3;       // 0..3 col-wave
  const int row0 = blockIdx.x * 128;

  const int s_rl0 = (w*2)*8 + (lane>>3);
  const int s_rl1 = (w*2+1)*8 + (lane>>3);
  const int ksw   = ((lane&7) ^ ((lane>>3)&7)) * 4;
  const float* gp0 = x + (size_t)min(row0 + s_rl0, N_NODES-1) * F_IN;
  const float* gp1 = x + (size_t)min(row0 + s_rl1, N_NODES-1) * F_IN;
  const char* l0 = smem + (w*2)*1024;       // + buf*16384
  const char* l1 = smem + (w*2+1)*1024;

  f32x4 acc[4][4] = {};

  #pragma unroll
  for (int p = 0; p < 2; ++p) {
    int kb = p*32 + ksw;
    const float* a0 = (kb + 4 <= F_IN) ? gp0 + kb : x;
    const float* a1 = (kb + 4 <= F_IN) ? gp1 + kb : x;
    gll16(a0, l0 + p*16384);
    gll16(a1, l1 + p*16384);
  }

  const short* bbase = W1S + (wc*64 + lr)*32 + quad*8;
  const int m2 = lr & 7;

  #pragma unroll
  for (int kc = 0; kc < 16; ++kc) {
    short8 bf4[4];
    #pragma unroll
    for (int t = 0; t < 4; ++t)
      bf4[t] = *(const short8*)(bbase + kc*8192 + t*16*32);
    __builtin_amdgcn_sched_barrier(0);

    if (kc < 14) {
      int kb = (kc+2)*32 + ksw;
      const float* a0 = (kb + 4 <= F_IN) ? gp0 + kb : x;
      const float* a1 = (kb + 4 <= F_IN) ? gp1 + kb : x;
      gll16(a0, l0 + ((kc+2)&3)*16384);
      gll16(a1, l1 + ((kc+2)&3)*16384);
      __builtin_amdgcn_sched_barrier(0);
      asm volatile("s_waitcnt vmcnt(8)" ::: "memory");
    } else if (kc == 14) {
      asm volatile("s_waitcnt vmcnt(6)" ::: "memory");
    } else {
      asm volatile("s_waitcnt vmcnt(4)" ::: "memory");
    }
    __builtin_amdgcn_s_barrier();

    const char* Abase = smem + (kc & 3)*16384;
    short8 af[4];
    #pragma unroll
    for (int t = 0; t < 4; ++t) {
      int rl = wr*64 + t*16 + lr;
      f32x4 u0 = *(const f32x4*)(Abase + rl*128 + (((quad*2  ) ^ m2) << 4));
      f32x4 u1 = *(const f32x4*)(Abase + rl*128 + (((quad*2+1) ^ m2) << 4));
      union { unsigned u[4]; short8 s; } pk;
      pk.u[0] = cvtpk(u0[0], u0[1]);
      pk.u[1] = cvtpk(u0[2], u0[3]);
      pk.u[2] = cvtpk(u1[0], u1[1]);
      pk.u[3] = cvtpk(u1[2], u1[3]);
      af[t] = pk.s;
    }

    #pragma unroll
    for (int rt = 0; rt < 4; ++rt)
      #pragma unroll
      for (int ct = 0; ct < 4; ++ct)
        acc[rt][ct] = __builtin_amdgcn_mfma_f32_16x16x32_bf16(af[rt], bf4[ct], acc[rt][ct], 0, 0, 0);
  }
  lbar();

  #pragma unroll
  for (int ct = 0; ct < 4; ++ct) {
    int col = wc*64 + ct*16 + lr;
    int cg = col >> 3, ci = col & 7;
    float bias = b1v[col];
    #pragma unroll
    for (int rt = 0; rt < 4; ++rt) {
      #pragma unroll
      for (int r = 0; r < 4; ++r) {
        int row = wr*64 + rt*16 + quad*4 + r;
        float v = fmaxf(acc[rt][ct][r] + bias, 0.f);
        Hl[row][((cg ^ (row & 31)) << 3) | ci] = f2bf(v);
      }
    }
  }
  lbar();

  f32x4 acc2[3] = {};
  const int arow = w*16 + lr;
  #pragma unroll
  for (int kc2 = 0; kc2 < 8; ++kc2) {
    int gg = kc2*4 + quad;
    short8 a2 = *(const short8*)&Hl[arow][(gg ^ (arow & 31)) << 3];
    #pragma unroll
    for (int nt = 0; nt < 3; ++nt) {
      short8 b2 = *(const short8*)(W2T + (nt*16 + lr)*256 + kc2*32 + quad*8);
      acc2[nt] = __builtin_amdgcn_mfma_f32_16x16x32_bf16(a2, b2, acc2[nt], 0, 0, 0);
    }
  }

  #pragma unroll
  for (int nt = 0; nt < 3; ++nt) {
    int col = nt*16 + lr;
    float bias = (col < C_OUT) ? b2v[col] : 0.f;
    #pragma unroll
    for (int r = 0; r < 4; ++r) {
      int row = row0 + w*16 + quad*4 + r;
      if (row < N_NODES) {
        float v = (col < C_OUT) ? (acc2[nt][r] + bias) : 0.f;
        h2b[(long)row * H2STRIDE + col] = f2bf(v);
      }
    }
  }
  {
    int col = 48 + lr;
    #pragma unroll
    for (int r = 0; r < 4; ++r) {
      int row = row0 + w*16 + quad*4 + r;
      if (row < N_NODES) h2b[(long)row * H2STRIDE + col] = 0;
    }
  }

  // ---- folded hist + per-chunk scan: block bid handles chunk bid ----
  if (blockIdx.x < NCH) {
    int cc = blockIdx.x;
    int* hcnt = (int*)smem;                    // 1568 ints (pad zeros)
    int* ssum = (int*)(smem + NBUCKP * 4);     // 512 ints
    lbar();
    for (int b = tid; b < NBUCKP; b += 512) hcnt[b] = 0;
    __syncthreads();
    int e0 = cc * CH, e1 = min(E, e0 + CH);    // e0 multiple of 4
    if (e0 < e1) {
      int g0 = e0 >> 2, g1 = e1 >> 2;
      const int4* rp = (const int4*)erow;
      for (int g = g0 + tid; g < g1; g += 512) {
        int4 r4 = rp[g];
        atomicAdd(&hcnt[r4.x >> 6], 1);
        atomicAdd(&hcnt[r4.y >> 6], 1);
        atomicAdd(&hcnt[r4.z >> 6], 1);
        atomicAdd(&hcnt[r4.w >> 6], 1);
      }
      for (int e = (g1 << 2) + tid; e < e1; e += 512)
        atomicAdd(&hcnt[erow[e] >> 6], 1);
    }
    __syncthreads();
    // block exclusive scan over 1568 counts (4 consecutive per thread)
    int base = tid * 4;
    int d0 = 0, d1 = 0, d2 = 0, d3 = 0, s = 0;
    if (base < NBUCKP) {
      d0 = hcnt[base]; d1 = hcnt[base+1]; d2 = hcnt[base+2]; d3 = hcnt[base+3];
      s = d0 + d1 + d2 + d3;
    }
    ssum[tid] = s;
    __syncthreads();
    for (int o = 1; o < 512; o <<= 1) {
      int u = (tid >= o) ? ssum[tid - o] : 0;
      __syncthreads();
      if (tid >= o) ssum[tid] += u;
      __syncthreads();
    }
    if (base < NBUCKP) {
      int run = ssum[tid] - s;
      int4 wv;
      wv.x = run;
      wv.y = run + d0;
      wv.z = run + d0 + d1;
      wv.w = run + d0 + d1 + d2;
      *(int4*)&lofs[(size_t)cc * NBUCKP + base] = wv;   // [NBUCK] = chunk total
    }
  }
}

// ---- K2: transpose lofs[c][b] -> lofsT[b][c] (rows 0..NBUCK inclusive).
__global__ __launch_bounds__(256) void k_transpose(
    const int* __restrict__ lofs, int* __restrict__ lofsT)
{
  __shared__ int t[64][65];
  int cb = blockIdx.x & 3;           // chunk tile (NCH/64 = 4)
  int bb = blockIdx.x >> 2;          // bucket tile (25 covers 1600)
  int c0 = cb * 64, b0 = bb * 64;
  int j  = threadIdx.x & 63;
  int i0 = threadIdx.x >> 6;
  #pragma unroll
  for (int k = 0; k < 16; ++k) {
    int i = i0 + k * 4;              // chunk offset
    int b = b0 + j;
    t[i][j] = (b <= NBUCK) ? lofs[(size_t)(c0 + i) * NBUCKP + b] : 0;
  }
  __syncthreads();
  #pragma unroll
  for (int k = 0; k < 16; ++k) {
    int i = i0 + k * 4;              // bucket offset
    int b = b0 + i;
    if (b <= NBUCK) lofsT[(size_t)b * NCH + c0 + j] = t[j][i];
  }
}

// ---- K3: split edges chunk-major. Block c writes ONLY into its own
// contiguous window sorted[c*CH .. c*CH+CH) at per-chunk prefix positions
// (open write lines L2-resident -> write amp ~1). LDS cursors from lofs.
__global__ __launch_bounds__(512) void k_split(
    const int* __restrict__ erow, const int* __restrict__ ecol,
    const float* __restrict__ eval, const int* __restrict__ lofs,
    int2* __restrict__ sorted, int E, int CH)
{
  __shared__ int cur[NBUCK];
  int tid = threadIdx.x, c = blockIdx.x;

  for (int b = tid; b < NBUCK; b += 512)
    cur[b] = lofs[(size_t)c * NBUCKP + b];   // per-chunk exclusive prefix
  __syncthreads();

  size_t obase = (size_t)c * CH;
  int e0 = c * CH, e1 = min(E, e0 + CH);
  if (e0 >= e1) return;
  int g0 = e0 >> 2, g1 = e1 >> 2;
  const int4*   rp = (const int4*)erow;
  const int4*   cp = (const int4*)ecol;
  const float4* vp = (const float4*)eval;
  for (int g = g0 + tid; g < g1; g += 512) {
    int4 r4 = rp[g];
    int4 c4 = cp[g];
    float4 v4 = vp[g];
    int p0 = atomicAdd(&cur[r4.x >> 6], 1);
    int p1 = atomicAdd(&cur[r4.y >> 6], 1);
    int p2 = atomicAdd(&cur[r4.z >> 6], 1);
    int p3 = atomicAdd(&cur[r4.w >> 6], 1);
    int2 cv;
    cv.x = c4.x | ((r4.x & 63) << 17); cv.y = __float_as_int(v4.x); sorted[obase + p0] = cv;
    cv.x = c4.y | ((r4.y & 63) << 17); cv.y = __float_as_int(v4.y); sorted[obase + p1] = cv;
    cv.x = c4.z | ((r4.z & 63) << 17); cv.y = __float_as_int(v4.z); sorted[obase + p2] = cv;
    cv.x = c4.w | ((r4.w & 63) << 17); cv.y = __float_as_int(v4.w); sorted[obase + p3] = cv;
  }
  for (int e = (g1 << 2) + tid; e < e1; e += 512) {
    int r = erow[e];
    int pos = atomicAdd(&cur[r >> 6], 1);
    int2 cv;
    cv.x = ecol[e] | ((r & 63) << 17);
    cv.y = __float_as_int(eval[e]);
    sorted[obase + pos] = cv;
  }
}

// ---- K4: bucket assembly + CSR sort (LDS) + wave-per-row SpMM + softmax.
// Block b gathers its 256 per-chunk segments (lofsT rows b,b+1 coalesced;
// hist fused into copy), LDS scan, LDS scatter, then 8 waves x 8 rows.
__global__ __launch_bounds__(512) void k_csr_spmm(
    const int* __restrict__ lofsT, const int2* __restrict__ sorted,
    const short* __restrict__ h2b, float* __restrict__ out, int CH)
{
  __shared__ int2 eraw[BCAPL];    // 14336 B
  __shared__ int2 eS[BCAPL];      // 14336 B
  __shared__ int sA[NCH];
  __shared__ int cntc[NCH];
  __shared__ int cpos[NCH];
  __shared__ int h[RPB], roff[RPB], cur[RPB];
  int tid = threadIdx.x, b = blockIdx.x;
  int lane = tid & 63, w = tid >> 6;

  if (tid < NCH) {
    int a  = lofsT[(size_t)b * NCH + tid];
    int e2 = lofsT[(size_t)(b + 1) * NCH + tid];
    sA[tid]   = a;
    cntc[tid] = e2 - a;
    cpos[tid] = e2 - a;
  }
  if (tid < RPB) h[tid] = 0;
  __syncthreads();
  // inclusive scan of cpos over 256 chunks
  for (int o = 1; o < NCH; o <<= 1) {
    int u = (tid >= o && tid < NCH) ? cpos[tid - o] : 0;
    __syncthreads();
    if (tid >= o && tid < NCH) cpos[tid] += u;
    __syncthreads();
  }
  int cntT = min(cpos[NCH - 1], BCAPL);

  // segment copy (2 threads per chunk) with fused row-histogram
  {
    int c    = tid & (NCH - 1);
    int half = tid >> 8;
    int srcb = c * CH + sA[c];
    int dstb = cpos[c] - cntc[c];
    int n    = cntc[c];
    for (int k = half; k < n; k += 2) {
      int p = dstb + k;
      if (p < BCAPL) {
        int2 cv = sorted[srcb + k];
        eraw[p] = cv;
        atomicAdd(&h[((unsigned)cv.x) >> 17], 1);
      }
    }
  }
  __syncthreads();
  // wave-0 inclusive shfl scan over 64 row counts
  if (w == 0) {
    int v = h[lane];
    int hv = v;
    #pragma unroll
    for (int o = 1; o < 64; o <<= 1) {
      int t = __shfl_up(v, o);
      if (lane >= o) v += t;
    }
    roff[lane] = v;
    cur[lane]  = v - hv;    // exclusive start
  }
  __syncthreads();
  // scatter into row-sorted LDS order
  for (int i = tid; i < cntT; i += 512) {
    int2 cv = eraw[i];
    int p = atomicAdd(&cur[((unsigned)cv.x) >> 17], 1);
    if (p < BCAPL) eS[p] = cv;
  }
  __syncthreads();

  // SpMM: wave w handles rows w*8 .. +7, 8-deep gather pipeline
  for (int rr = 0; rr < 8; ++rr) {
    int r = w * 8 + rr;
    int row = b * RPB + r;
    if (row >= N_NODES) continue;
    float acc = ALPHA0 * bf2f(h2b[(size_t)row * H2STRIDE + lane]);  // 0 for lane>=40
    int e  = roff[r] - h[r];
    int ee = roff[r];
    for (; e + 7 < ee; e += 8) {
      int2 cc[8];
      float gg[8];
      #pragma unroll
      for (int j = 0; j < 8; ++j) cc[j] = eS[e + j];
      #pragma unroll
      for (int j = 0; j < 8; ++j)
        gg[j] = bf2f(h2b[(size_t)(cc[j].x & 0x1FFFF) * H2STRIDE + lane]);
      #pragma unroll
      for (int j = 0; j < 8; ++j) acc += __int_as_float(cc[j].y) * gg[j];
    }
    for (; e + 3 < ee; e += 4) {
      int2 c0 = eS[e], c1 = eS[e+1], c2 = eS[e+2], c3 = eS[e+3];
      float g0 = bf2f(h2b[(size_t)(c0.x & 0x1FFFF) * H2STRIDE + lane]);
      float g1 = bf2f(h2b[(size_t)(c1.x & 0x1FFFF) * H2STRIDE + lane]);
      float g2 = bf2f(h2b[(size_t)(c2.x & 0x1FFFF) * H2STRIDE + lane]);
      float g3 = bf2f(h2b[(size_t)(c3.x & 0x1FFFF) * H2STRIDE + lane]);
      acc += __int_as_float(c0.y) * g0;
      acc += __int_as_float(c1.y) * g1;
      acc += __int_as_float(c2.y) * g2;
      acc += __int_as_float(c3.y) * g3;
    }
    for (; e < ee; ++e) {
      int2 c0 = eS[e];
      acc += __int_as_float(c0.y) * bf2f(h2b[(size_t)(c0.x & 0x1FFFF) * H2STRIDE + lane]);
    }
    float m = (lane < C_OUT) ? acc : -INFINITY;
    #pragma unroll
    for (int o = 32; o > 0; o >>= 1) m = fmaxf(m, __shfl_xor(m, o));
    float ev = (lane < C_OUT) ? __expf(acc - m) : 0.f;
    float s = ev;
    #pragma unroll
    for (int o = 32; o > 0; o >>= 1) s += __shfl_xor(s, o);
    if (lane < C_OUT) out[(long)row * C_OUT + lane] = acc - m - __logf(s);
  }
}

extern "C" void kernel_launch(void* const* d_in, const int* in_sizes, int n_in,
                              void* d_out, int out_size, void* d_ws, size_t ws_size,
                              hipStream_t stream) {
  const float* x    = (const float*)d_in[0];
  const float* W1   = (const float*)d_in[1];
  const float* b1   = (const float*)d_in[2];
  const float* W2   = (const float*)d_in[3];
  const float* b2   = (const float*)d_in[4];
  const int*   erow = (const int*)d_in[5];
  const int*   ecol = (const int*)d_in[6];
  const float* eval = (const float*)d_in[7];
  const int E  = in_sizes[5];
  int CH = (E + NCH - 1) / NCH;
  CH = (CH + 3) & ~3;                 // multiple of 4 for int4 alignment

  // ws: h2b 12.8MB | W1S 256KB | W2T 24KB | lofs 1.6MB | lofsT 1.6MB |
  //     sorted NCH*CH*8 (~18.4MB)   (~35 MB)
  char* p = (char*)d_ws;
  short* h2b    = (short*)p;  p += (size_t)N_NODES * H2STRIDE * 2;
  short* W1S    = (short*)p;  p += (size_t)16*256*32 * 2;
  short* W2T    = (short*)p;  p += (size_t)48*256 * 2;
  int*   lofs   = (int*)p;    p += (size_t)NCH * NBUCKP * 4;
  int*   lofsT  = (int*)p;    p += (size_t)1600 * NCH * 4;
  int2*  sorted = (int2*)p;
  float* out = (float*)d_out;

  k_pack_weights<<<(16*256*32 + 48*256 + 255)/256, 256, 0, stream>>>(W1, W2, W1S, W2T);
  k_fused_mlp<<<(N_NODES + 127)/128, 512, 0, stream>>>(x, b1, b2, W1S, W2T, h2b,
                                                       erow, lofs, E, CH);
  k_transpose<<<4 * 25, 256, 0, stream>>>(lofs, lofsT);
  k_split<<<NCH, 512, 0, stream>>>(erow, ecol, eval, lofs, sorted, E, CH);
  k_csr_spmm<<<NBUCK, 512, 0, stream>>>(lofsT, sorted, h2b, out, CH);
}

// Round 12
// 456.981 us; speedup vs baseline: 2.4803x; 1.0136x over previous
//
#include <hip/hip_runtime.h>
#include <hip/hip_bf16.h>

// LSAPPNP: h = relu(x@W1+b1); h2 = h@W2+b2; agg[r] += val*h2[c] over edges;
// out = log_softmax(0.1*h2 + agg, axis=1)
// N=100000, F_IN=500, HID=256, C=40, E~2.3M
//
// Round 18: MLP occupancy fix. All prior MLP variants used 128-row/64KB
// tiles -> 2 blocks/CU, 16 waves/CU (35% occ) — the invariant behind the
// ~130us plateau (latency-bound, all pipes idle). Now 64 rows x 256 cols,
// 256 thr (4 waves), 32KB LDS -> 5 blocks/CU, 20 waves/CU (~62% occ cap),
// 2.5x more independent gll streams, smaller barrier groups. Same R8
// schedule. Edge pipeline byte-identical to R17 (463.2us).

#define N_NODES 100000
#define F_IN    500
#define HID     256
#define C_OUT   40
#define ALPHA0  0.1f
#define H2STRIDE 64

#define RPB     64                            // rows per bucket
#define NBUCK   ((N_NODES + RPB - 1) / RPB)   // 1563
#define NBUCKP  1568                          // padded (x32, >= NBUCK+1)
#define NCH     256                           // edge chunks
#define BCAPL   1792                          // bucket cap (mean 1474, +8.3 sigma)

typedef short short8 __attribute__((ext_vector_type(8)));
typedef float f32x4  __attribute__((ext_vector_type(4)));

__device__ __forceinline__ short f2bf(float f) {
  union { float f; unsigned u; } x; x.f = f;
  unsigned r = x.u + 0x7fffu + ((x.u >> 16) & 1u);  // RNE
  return (short)(r >> 16);
}
__device__ __forceinline__ float bf2f(short s) {
  union { unsigned u; float f; } x; x.u = ((unsigned)(unsigned short)s) << 16;
  return x.f;
}
// packed f32x2 -> bf16x2 (RNE), single VOP3
__device__ __forceinline__ unsigned cvtpk(float lo, float hi) {
  unsigned r;
  asm("v_cvt_pk_bf16_f32 %0, %1, %2" : "=v"(r) : "v"(lo), "v"(hi));
  return r;
}
// LDS-only barrier: drain DS ops, then raw s_barrier (no vmcnt drain).
__device__ __forceinline__ void lbar() {
  asm volatile("s_waitcnt lgkmcnt(0)" ::: "memory");
  __builtin_amdgcn_s_barrier();
}
// async global->LDS, 16B per lane; LDS dest = wave-uniform base + lane*16
__device__ __forceinline__ void gll16(const float* g, const char* l) {
  __builtin_amdgcn_global_load_lds(
      (const __attribute__((address_space(1))) void*)g,
      (__attribute__((address_space(3))) void*)l, 16, 0, 0);
}

// ---- K0: pack W1 -> W1S [16 kc][256 n][32 k] bf16; W2 -> W2T [48 n][256 k]
__global__ __launch_bounds__(256) void k_pack_weights(
    const float* __restrict__ W1, const float* __restrict__ W2,
    short* __restrict__ W1S, short* __restrict__ W2T)
{
  int i = blockIdx.x * 256 + threadIdx.x;
  if (i < 16*256*32) {
    int kc  = i >> 13;
    int idx = i & 8191;
    int n   = idx >> 5;
    int kk  = idx & 31;
    int k   = kc*32 + kk;
    float v = (k < F_IN) ? W1[k*HID + n] : 0.f;
    W1S[i] = f2bf(v);
  } else {
    int j = i - 16*256*32;
    if (j < 48*256) {
      int n = j >> 8;
      int k = j & 255;
      float v = (n < C_OUT) ? W2[k*C_OUT + n] : 0.f;
      W2T[j] = f2bf(v);
    }
  }
}

// ---- K1: fused MLP, 64-row tile, 256 thr = 4 waves (each wave: all 64
// rows x 64-col slice). A: gll f32 into 4x8KB rotating buffers, counted
// vmcnt, light barriers. Hl overlay 32KB. Folded hist+scan post-phase
// (blocks 0..NCH-1). 5 blocks/CU.
__global__ __launch_bounds__(256, 4) void k_fused_mlp(
    const float* __restrict__ x, const float* __restrict__ b1v,
    const float* __restrict__ b2v,
    const short* __restrict__ W1S, const short* __restrict__ W2T,
    short* __restrict__ h2b,
    const int* __restrict__ erow, int* __restrict__ lofs, int E, int CH)
{
  __shared__ __align__(16) char smem[32768];
  short (*Hl)[256] = (short(*)[256])smem;   // post-loop overlay, 32KB

  const int tid  = threadIdx.x;
  const int w    = tid >> 6;      // 0..3 = col-wave
  const int lane = tid & 63;
  const int lr   = lane & 15;
  const int quad = lane >> 4;
  const int row0 = blockIdx.x * 64;

  // staging: wave w owns chunks 2w, 2w+1 (rows 16w..16w+15, 8 rows/chunk)
  const int s_rl0 = (w*2)*8 + (lane>>3);
  const int s_rl1 = (w*2+1)*8 + (lane>>3);
  const int ksw   = ((lane&7) ^ ((lane>>3)&7)) * 4;
  const float* gp0 = x + (size_t)min(row0 + s_rl0, N_NODES-1) * F_IN;
  const float* gp1 = x + (size_t)min(row0 + s_rl1, N_NODES-1) * F_IN;
  const char* l0 = smem + (w*2)*1024;       // + buf*8192
  const char* l1 = smem + (w*2+1)*1024;

  f32x4 acc[4][4] = {};

  #pragma unroll
  for (int p = 0; p < 2; ++p) {
    int kb = p*32 + ksw;
    const float* a0 = (kb + 4 <= F_IN) ? gp0 + kb : x;
    const float* a1 = (kb + 4 <= F_IN) ? gp1 + kb : x;
    gll16(a0, l0 + p*8192);
    gll16(a1, l1 + p*8192);
  }

  const short* bbase = W1S + (w*64 + lr)*32 + quad*8;
  const int m2 = lr & 7;

  #pragma unroll
  for (int kc = 0; kc < 16; ++kc) {
    short8 bf4[4];
    #pragma unroll
    for (int t = 0; t < 4; ++t)
      bf4[t] = *(const short8*)(bbase + kc*8192 + t*16*32);
    __builtin_amdgcn_sched_barrier(0);

    if (kc < 14) {
      int kb = (kc+2)*32 + ksw;
      const float* a0 = (kb + 4 <= F_IN) ? gp0 + kb : x;
      const float* a1 = (kb + 4 <= F_IN) ? gp1 + kb : x;
      gll16(a0, l0 + ((kc+2)&3)*8192);
      gll16(a1, l1 + ((kc+2)&3)*8192);
      __builtin_amdgcn_sched_barrier(0);
      asm volatile("s_waitcnt vmcnt(8)" ::: "memory");
    } else if (kc == 14) {
      asm volatile("s_waitcnt vmcnt(6)" ::: "memory");
    } else {
      asm volatile("s_waitcnt vmcnt(4)" ::: "memory");
    }
    __builtin_amdgcn_s_barrier();

    const char* Abase = smem + (kc & 3)*8192;
    short8 af[4];
    #pragma unroll
    for (int t = 0; t < 4; ++t) {
      int rl = t*16 + lr;     // wave spans all 64 rows
      f32x4 u0 = *(const f32x4*)(Abase + rl*128 + (((quad*2  ) ^ m2) << 4));
      f32x4 u1 = *(const f32x4*)(Abase + rl*128 + (((quad*2+1) ^ m2) << 4));
      union { unsigned u[4]; short8 s; } pk;
      pk.u[0] = cvtpk(u0[0], u0[1]);
      pk.u[1] = cvtpk(u0[2], u0[3]);
      pk.u[2] = cvtpk(u1[0], u1[1]);
      pk.u[3] = cvtpk(u1[2], u1[3]);
      af[t] = pk.s;
    }

    #pragma unroll
    for (int rt = 0; rt < 4; ++rt)
      #pragma unroll
      for (int ct = 0; ct < 4; ++ct)
        acc[rt][ct] = __builtin_amdgcn_mfma_f32_16x16x32_bf16(af[rt], bf4[ct], acc[rt][ct], 0, 0, 0);
  }
  lbar();

  // epilogue 1: relu(acc + b1) -> Hl[64][256] (XOR-swizzled col groups)
  #pragma unroll
  for (int ct = 0; ct < 4; ++ct) {
    int col = w*64 + ct*16 + lr;
    int cg = col >> 3, ci = col & 7;
    float bias = b1v[col];
    #pragma unroll
    for (int rt = 0; rt < 4; ++rt) {
      #pragma unroll
      for (int r = 0; r < 4; ++r) {
        int row = rt*16 + quad*4 + r;
        float v = fmaxf(acc[rt][ct][r] + bias, 0.f);
        Hl[row][((cg ^ (row & 31)) << 3) | ci] = f2bf(v);
      }
    }
  }
  lbar();

  // GEMM2: wave w handles rows w*16..+15, 48 padded cols, K=256
  f32x4 acc2[3] = {};
  const int arow = w*16 + lr;
  #pragma unroll
  for (int kc2 = 0; kc2 < 8; ++kc2) {
    int gg = kc2*4 + quad;
    short8 a2 = *(const short8*)&Hl[arow][(gg ^ (arow & 31)) << 3];
    #pragma unroll
    for (int nt = 0; nt < 3; ++nt) {
      short8 b2 = *(const short8*)(W2T + (nt*16 + lr)*256 + kc2*32 + quad*8);
      acc2[nt] = __builtin_amdgcn_mfma_f32_16x16x32_bf16(a2, b2, acc2[nt], 0, 0, 0);
    }
  }

  // epilogue 2: h2b = bf16(acc2 + b2), stride 64, cols >= C_OUT zeroed
  #pragma unroll
  for (int nt = 0; nt < 3; ++nt) {
    int col = nt*16 + lr;
    float bias = (col < C_OUT) ? b2v[col] : 0.f;
    #pragma unroll
    for (int r = 0; r < 4; ++r) {
      int row = row0 + w*16 + quad*4 + r;
      if (row < N_NODES) {
        float v = (col < C_OUT) ? (acc2[nt][r] + bias) : 0.f;
        h2b[(long)row * H2STRIDE + col] = f2bf(v);
      }
    }
  }
  {
    int col = 48 + lr;
    #pragma unroll
    for (int r = 0; r < 4; ++r) {
      int row = row0 + w*16 + quad*4 + r;
      if (row < N_NODES) h2b[(long)row * H2STRIDE + col] = 0;
    }
  }

  // ---- folded hist + per-chunk scan: block bid handles chunk bid ----
  if (blockIdx.x < NCH) {
    int cc = blockIdx.x;
    int* hcnt = (int*)smem;                    // 1568 ints
    int* ssum = (int*)(smem + NBUCKP * 4);     // 256 ints
    lbar();                                    // Hl reads drained
    for (int b = tid; b < NBUCKP; b += 256) hcnt[b] = 0;
    __syncthreads();
    int e0 = cc * CH, e1 = min(E, e0 + CH);    // e0 multiple of 4
    if (e0 < e1) {
      int g0 = e0 >> 2, g1 = e1 >> 2;
      const int4* rp = (const int4*)erow;
      for (int g = g0 + tid; g < g1; g += 256) {
        int4 r4 = rp[g];
        atomicAdd(&hcnt[r4.x >> 6], 1);
        atomicAdd(&hcnt[r4.y >> 6], 1);
        atomicAdd(&hcnt[r4.z >> 6], 1);
        atomicAdd(&hcnt[r4.w >> 6], 1);
      }
      for (int e = (g1 << 2) + tid; e < e1; e += 256)
        atomicAdd(&hcnt[erow[e] >> 6], 1);
    }
    __syncthreads();
    // block exclusive scan over 1568 counts (8 consecutive per thread)
    int base = tid * 8;
    int d[8];
    int s = 0;
    #pragma unroll
    for (int k = 0; k < 8; ++k) {
      d[k] = (base + k < NBUCKP) ? hcnt[base + k] : 0;
      s += d[k];
    }
    ssum[tid] = s;
    __syncthreads();
    for (int o = 1; o < 256; o <<= 1) {
      int u = (tid >= o) ? ssum[tid - o] : 0;
      __syncthreads();
      if (tid >= o) ssum[tid] += u;
      __syncthreads();
    }
    int run = ssum[tid] - s;
    #pragma unroll
    for (int k = 0; k < 8; ++k) {
      if (base + k < NBUCKP) lofs[(size_t)cc * NBUCKP + base + k] = run;
      run += d[k];
    }
  }
}

// ---- K2: transpose lofs[c][b] -> lofsT[b][c] (rows 0..NBUCK inclusive).
__global__ __launch_bounds__(256) void k_transpose(
    const int* __restrict__ lofs, int* __restrict__ lofsT)
{
  __shared__ int t[64][65];
  int cb = blockIdx.x & 3;           // chunk tile (NCH/64 = 4)
  int bb = blockIdx.x >> 2;          // bucket tile (25 covers 1600)
  int c0 = cb * 64, b0 = bb * 64;
  int j  = threadIdx.x & 63;
  int i0 = threadIdx.x >> 6;
  #pragma unroll
  for (int k = 0; k < 16; ++k) {
    int i = i0 + k * 4;              // chunk offset
    int b = b0 + j;
    t[i][j] = (b <= NBUCK) ? lofs[(size_t)(c0 + i) * NBUCKP + b] : 0;
  }
  __syncthreads();
  #pragma unroll
  for (int k = 0; k < 16; ++k) {
    int i = i0 + k * 4;              // bucket offset
    int b = b0 + i;
    if (b <= NBUCK) lofsT[(size_t)b * NCH + c0 + j] = t[j][i];
  }
}

// ---- K3: split edges chunk-major. Block c writes ONLY into its own
// contiguous window sorted[c*CH .. c*CH+CH) at per-chunk prefix positions.
__global__ __launch_bounds__(512) void k_split(
    const int* __restrict__ erow, const int* __restrict__ ecol,
    const float* __restrict__ eval, const int* __restrict__ lofs,
    int2* __restrict__ sorted, int E, int CH)
{
  __shared__ int cur[NBUCK];
  int tid = threadIdx.x, c = blockIdx.x;

  for (int b = tid; b < NBUCK; b += 512)
    cur[b] = lofs[(size_t)c * NBUCKP + b];   // per-chunk exclusive prefix
  __syncthreads();

  size_t obase = (size_t)c * CH;
  int e0 = c * CH, e1 = min(E, e0 + CH);
  if (e0 >= e1) return;
  int g0 = e0 >> 2, g1 = e1 >> 2;
  const int4*   rp = (const int4*)erow;
  const int4*   cp = (const int4*)ecol;
  const float4* vp = (const float4*)eval;
  for (int g = g0 + tid; g < g1; g += 512) {
    int4 r4 = rp[g];
    int4 c4 = cp[g];
    float4 v4 = vp[g];
    int p0 = atomicAdd(&cur[r4.x >> 6], 1);
    int p1 = atomicAdd(&cur[r4.y >> 6], 1);
    int p2 = atomicAdd(&cur[r4.z >> 6], 1);
    int p3 = atomicAdd(&cur[r4.w >> 6], 1);
    int2 cv;
    cv.x = c4.x | ((r4.x & 63) << 17); cv.y = __float_as_int(v4.x); sorted[obase + p0] = cv;
    cv.x = c4.y | ((r4.y & 63) << 17); cv.y = __float_as_int(v4.y); sorted[obase + p1] = cv;
    cv.x = c4.z | ((r4.z & 63) << 17); cv.y = __float_as_int(v4.z); sorted[obase + p2] = cv;
    cv.x = c4.w | ((r4.w & 63) << 17); cv.y = __float_as_int(v4.w); sorted[obase + p3] = cv;
  }
  for (int e = (g1 << 2) + tid; e < e1; e += 512) {
    int r = erow[e];
    int pos = atomicAdd(&cur[r >> 6], 1);
    int2 cv;
    cv.x = ecol[e] | ((r & 63) << 17);
    cv.y = __float_as_int(eval[e]);
    sorted[obase + pos] = cv;
  }
}

// ---- K4: bucket assembly + CSR sort (LDS) + wave-per-row SpMM + softmax.
__global__ __launch_bounds__(512) void k_csr_spmm(
    const int* __restrict__ lofsT, const int2* __restrict__ sorted,
    const short* __restrict__ h2b, float* __restrict__ out, int CH)
{
  __shared__ int2 eraw[BCAPL];    // 14336 B
  __shared__ int2 eS[BCAPL];      // 14336 B
  __shared__ int sA[NCH];
  __shared__ int cntc[NCH];
  __shared__ int cpos[NCH];
  __shared__ int h[RPB], roff[RPB], cur[RPB];
  int tid = threadIdx.x, b = blockIdx.x;
  int lane = tid & 63, w = tid >> 6;

  if (tid < NCH) {
    int a  = lofsT[(size_t)b * NCH + tid];
    int e2 = lofsT[(size_t)(b + 1) * NCH + tid];
    sA[tid]   = a;
    cntc[tid] = e2 - a;
    cpos[tid] = e2 - a;
  }
  if (tid < RPB) h[tid] = 0;
  __syncthreads();
  // inclusive scan of cpos over 256 chunks
  for (int o = 1; o < NCH; o <<= 1) {
    int u = (tid >= o && tid < NCH) ? cpos[tid - o] : 0;
    __syncthreads();
    if (tid >= o && tid < NCH) cpos[tid] += u;
    __syncthreads();
  }
  int cntT = min(cpos[NCH - 1], BCAPL);

  // segment copy (2 threads per chunk) with fused row-histogram
  {
    int c    = tid & (NCH - 1);
    int half = tid >> 8;
    int srcb = c * CH + sA[c];
    int dstb = cpos[c] - cntc[c];
    int n    = cntc[c];
    for (int k = half; k < n; k += 2) {
      int p = dstb + k;
      if (p < BCAPL) {
        int2 cv = sorted[srcb + k];
        eraw[p] = cv;
        atomicAdd(&h[((unsigned)cv.x) >> 17], 1);
      }
    }
  }
  __syncthreads();
  // wave-0 inclusive shfl scan over 64 row counts
  if (w == 0) {
    int v = h[lane];
    int hv = v;
    #pragma unroll
    for (int o = 1; o < 64; o <<= 1) {
      int t = __shfl_up(v, o);
      if (lane >= o) v += t;
    }
    roff[lane] = v;
    cur[lane]  = v - hv;    // exclusive start
  }
  __syncthreads();
  // scatter into row-sorted LDS order
  for (int i = tid; i < cntT; i += 512) {
    int2 cv = eraw[i];
    int p = atomicAdd(&cur[((unsigned)cv.x) >> 17], 1);
    if (p < BCAPL) eS[p] = cv;
  }
  __syncthreads();

  // SpMM: wave w handles rows w*8 .. +7, 8-deep gather pipeline
  for (int rr = 0; rr < 8; ++rr) {
    int r = w * 8 + rr;
    int row = b * RPB + r;
    if (row >= N_NODES) continue;
    float acc = ALPHA0 * bf2f(h2b[(size_t)row * H2STRIDE + lane]);  // 0 for lane>=40
    int e  = roff[r] - h[r];
    int ee = roff[r];
    for (; e + 7 < ee; e += 8) {
      int2 cc[8];
      float gg[8];
      #pragma unroll
      for (int j = 0; j < 8; ++j) cc[j] = eS[e + j];
      #pragma unroll
      for (int j = 0; j < 8; ++j)
        gg[j] = bf2f(h2b[(size_t)(cc[j].x & 0x1FFFF) * H2STRIDE + lane]);
      #pragma unroll
      for (int j = 0; j < 8; ++j) acc += __int_as_float(cc[j].y) * gg[j];
    }
    for (; e + 3 < ee; e += 4) {
      int2 c0 = eS[e], c1 = eS[e+1], c2 = eS[e+2], c3 = eS[e+3];
      float g0 = bf2f(h2b[(size_t)(c0.x & 0x1FFFF) * H2STRIDE + lane]);
      float g1 = bf2f(h2b[(size_t)(c1.x & 0x1FFFF) * H2STRIDE + lane]);
      float g2 = bf2f(h2b[(size_t)(c2.x & 0x1FFFF) * H2STRIDE + lane]);
      float g3 = bf2f(h2b[(size_t)(c3.x & 0x1FFFF) * H2STRIDE + lane]);
      acc += __int_as_float(c0.y) * g0;
      acc += __int_as_float(c1.y) * g1;
      acc += __int_as_float(c2.y) * g2;
      acc += __int_as_float(c3.y) * g3;
    }
    for (; e < ee; ++e) {
      int2 c0 = eS[e];
      acc += __int_as_float(c0.y) * bf2f(h2b[(size_t)(c0.x & 0x1FFFF) * H2STRIDE + lane]);
    }
    float m = (lane < C_OUT) ? acc : -INFINITY;
    #pragma unroll
    for (int o = 32; o > 0; o >>= 1) m = fmaxf(m, __shfl_xor(m, o));
    float ev = (lane < C_OUT) ? __expf(acc - m) : 0.f;
    float s = ev;
    #pragma unroll
    for (int o = 32; o > 0; o >>= 1) s += __shfl_xor(s, o);
    if (lane < C_OUT) out[(long)row * C_OUT + lane] = acc - m - __logf(s);
  }
}

extern "C" void kernel_launch(void* const* d_in, const int* in_sizes, int n_in,
                              void* d_out, int out_size, void* d_ws, size_t ws_size,
                              hipStream_t stream) {
  const float* x    = (const float*)d_in[0];
  const float* W1   = (const float*)d_in[1];
  const float* b1   = (const float*)d_in[2];
  const float* W2   = (const float*)d_in[3];
  const float* b2   = (const float*)d_in[4];
  const int*   erow = (const int*)d_in[5];
  const int*   ecol = (const int*)d_in[6];
  const float* eval = (const float*)d_in[7];
  const int E  = in_sizes[5];
  int CH = (E + NCH - 1) / NCH;
  CH = (CH + 3) & ~3;                 // multiple of 4 for int4 alignment

  // ws: h2b 12.8MB | W1S 256KB | W2T 24KB | lofs 1.6MB | lofsT 1.6MB |
  //     sorted NCH*CH*8 (~18.4MB)   (~35 MB)
  char* p = (char*)d_ws;
  short* h2b    = (short*)p;  p += (size_t)N_NODES * H2STRIDE * 2;
  short* W1S    = (short*)p;  p += (size_t)16*256*32 * 2;
  short* W2T    = (short*)p;  p += (size_t)48*256 * 2;
  int*   lofs   = (int*)p;    p += (size_t)NCH * NBUCKP * 4;
  int*   lofsT  = (int*)p;    p += (size_t)1600 * NCH * 4;
  int2*  sorted = (int2*)p;
  float* out = (float*)d_out;

  k_pack_weights<<<(16*256*32 + 48*256 + 255)/256, 256, 0, stream>>>(W1, W2, W1S, W2T);
  k_fused_mlp<<<(N_NODES + 63)/64, 256, 0, stream>>>(x, b1, b2, W1S, W2T, h2b,
                                                     erow, lofs, E, CH);
  k_transpose<<<4 * 25, 256, 0, stream>>>(lofs, lofsT);
  k_split<<<NCH, 512, 0, stream>>>(erow, ecol, eval, lofs, sorted, E, CH);
  k_csr_spmm<<<NBUCK, 512, 0, stream>>>(lofsT, sorted, h2b, out, CH);
}